// Round 1
// baseline (623.676 us; speedup 1.0000x reference)
//
#include <hip/hip_runtime.h>

typedef unsigned short ushort_t;
typedef __attribute__((ext_vector_type(8))) short bs8;       // 8 x bf16 (4 VGPR)
typedef __attribute__((ext_vector_type(4))) float f32x4;
typedef __attribute__((ext_vector_type(4))) unsigned short u16x4;

#define DEV __device__ __forceinline__

DEV unsigned short f2bf(float f){
  unsigned u = __float_as_uint(f);
  u += 0x7fffu + ((u >> 16) & 1u);           // round-to-nearest-even
  return (unsigned short)(u >> 16);
}
DEV float bf2f(unsigned short h){ return __uint_as_float(((unsigned)h) << 16); }

DEV void gl2lds16(const void* g, void* l){
  __builtin_amdgcn_global_load_lds((const __attribute__((address_space(1))) void*)g,
                                   (__attribute__((address_space(3))) void*)l, 16, 0, 0);
}

DEV void st_out(ushort_t* C, size_t i, float v){ C[i] = f2bf(v); }
DEV void st_out(float*    C, size_t i, float v){ C[i] = v; }

// ---------------- cast x (fp32 -> bf16), 4 elems/thread ----------------
__global__ __launch_bounds__(256) void cast_x(const float* __restrict__ in,
                                              ushort_t* __restrict__ outb){
  size_t i = ((size_t)blockIdx.x * 256 + threadIdx.x) * 4;
  float4 v = *(const float4*)(in + i);
  u16x4 o;
  o[0] = f2bf(v.x); o[1] = f2bf(v.y); o[2] = f2bf(v.z); o[3] = f2bf(v.w);
  *(u16x4*)(outb + i) = o;
}

// ---------------- transpose-cast weight: in[K][N] fp32 -> out[N][K] bf16 ----------------
__global__ __launch_bounds__(256) void transpose_cast(const float* __restrict__ in,
                                                      ushort_t* __restrict__ out,
                                                      int K, int N){
  __shared__ float tile[32][33];
  int k0 = blockIdx.y * 32, n0 = blockIdx.x * 32;
  int tx = threadIdx.x, ty = threadIdx.y;
  for (int r = ty; r < 32; r += 8)
    tile[r][tx] = in[(size_t)(k0 + r) * N + n0 + tx];
  __syncthreads();
  for (int r = ty; r < 32; r += 8)
    out[(size_t)(n0 + r) * K + k0 + tx] = f2bf(tile[tx][r]);
}

// ---------------- bf16 transpose per (b,h): v[M][2048] -> vT[BH][128][T] ----------------
__global__ __launch_bounds__(256) void transpose_v(const ushort_t* __restrict__ v,
                                                   ushort_t* __restrict__ vT){
  __shared__ ushort_t tile[32][33];
  int bh = blockIdx.z; int b = bh >> 4, h = bh & 15;
  int t0 = blockIdx.x * 32, d0 = blockIdx.y * 32;
  int tx = threadIdx.x, ty = threadIdx.y;
  for (int r = ty; r < 32; r += 8)
    tile[r][tx] = v[((size_t)(b * 2048 + t0 + r)) * 2048 + h * 128 + d0 + tx];
  __syncthreads();
  for (int r = ty; r < 32; r += 8)
    vT[((size_t)bh * 128 + d0 + r) * 2048 + t0 + tx] = tile[tx][r];
}

// ---------------- assemble Q or K: concat core[M][2048] + rope(rot[M][1024]) -> [BH][T][192] ----------------
__global__ __launch_bounds__(256) void assemble_qk(const ushort_t* __restrict__ core,
                                                   const ushort_t* __restrict__ rot,
                                                   const float* __restrict__ fc,
                                                   const float* __restrict__ fs,
                                                   ushort_t* __restrict__ outb){
  const int m = blockIdx.x;
  const int b = m >> 11, t = m & 2047;
  for (int i = threadIdx.x; i < 2048; i += 256){
    int h = i >> 7, d = i & 127;
    outb[((size_t)(b * 16 + h) * 2048 + t) * 192 + d] = core[(size_t)m * 2048 + i];
  }
  for (int p = threadIdx.x; p < 512; p += 256){
    int h = p >> 5, i = p & 31;
    float tr = bf2f(rot[(size_t)m * 1024 + h * 64 + 2 * i]);
    float ti = bf2f(rot[(size_t)m * 1024 + h * 64 + 2 * i + 1]);
    float c = fc[t * 32 + i], s = fs[t * 32 + i];
    size_t base = ((size_t)(b * 16 + h) * 2048 + t) * 192 + 128;
    outb[base + 2 * i]     = f2bf(tr * c - ti * s);
    outb[base + 2 * i + 1] = f2bf(tr * s + ti * c);
  }
}

// ---------------- GEMM: C[M][N] = A[M][K] @ BT[N][K]^T   (m97-style 128x128, BK=32) ----------------
template<typename OT>
__global__ __launch_bounds__(256) void gemm_bt(const ushort_t* __restrict__ A,
                                               const ushort_t* __restrict__ BT,
                                               OT* __restrict__ C,
                                               int M, int N, int K){
  __shared__ __align__(16) ushort_t As[128 * 32];
  __shared__ __align__(16) ushort_t Bs[128 * 32];
  const int tid = threadIdx.x;
  const int lane = tid & 63;
  const int wid = tid >> 6;
  const int l15 = lane & 15;
  const int kf = (lane >> 4) * 8;
  const int m0 = blockIdx.x * 128;
  const int n0 = blockIdx.y * 128;
  const int wr = wid >> 1, wc = wid & 1;

  const int c0 = tid, c1 = tid + 256;           // 16B chunks: row=c>>2, col8=(c&3)*8
  const ushort_t* a0 = A + (size_t)(m0 + (c0 >> 2)) * K + (c0 & 3) * 8;
  const ushort_t* a1 = A + (size_t)(m0 + (c1 >> 2)) * K + (c1 & 3) * 8;
  const ushort_t* b0 = BT + (size_t)(n0 + (c0 >> 2)) * K + (c0 & 3) * 8;
  const ushort_t* b1 = BT + (size_t)(n0 + (c1 >> 2)) * K + (c1 & 3) * 8;
  ushort_t* la0 = As + c0 * 8;
  ushort_t* la1 = As + c1 * 8;
  ushort_t* lb0 = Bs + c0 * 8;
  ushort_t* lb1 = Bs + c1 * 8;

  f32x4 acc[4][4] = {};

  for (int k0 = 0; k0 < K; k0 += 32){
    gl2lds16(a0 + k0, la0);
    gl2lds16(a1 + k0, la1);
    gl2lds16(b0 + k0, lb0);
    gl2lds16(b1 + k0, lb1);
    __syncthreads();
    bs8 af[4], bfv[4];
#pragma unroll
    for (int m = 0; m < 4; ++m)
      af[m] = *(const bs8*)(As + (wr * 64 + m * 16 + l15) * 32 + kf);
#pragma unroll
    for (int n = 0; n < 4; ++n)
      bfv[n] = *(const bs8*)(Bs + (wc * 64 + n * 16 + l15) * 32 + kf);
#pragma unroll
    for (int m = 0; m < 4; ++m)
#pragma unroll
      for (int n = 0; n < 4; ++n)
        acc[m][n] = __builtin_amdgcn_mfma_f32_16x16x32_bf16(af[m], bfv[n], acc[m][n], 0, 0, 0);
    __syncthreads();
  }

#pragma unroll
  for (int m = 0; m < 4; ++m){
    const int r0 = m0 + wr * 64 + m * 16 + (lane >> 4) * 4;
#pragma unroll
    for (int n = 0; n < 4; ++n){
      const int cc = n0 + wc * 64 + n * 16 + l15;
#pragma unroll
      for (int j = 0; j < 4; ++j)
        st_out(C, (size_t)(r0 + j) * N + cc, acc[m][n][j]);
    }
  }
}

// ---------------- flash attention: Q[BH][T][192], K[BH][T][192], VT[BH][128][T] -> O[M][2048] ----------------
__global__ __launch_bounds__(256) void attn_kernel(const ushort_t* __restrict__ Qa,
                                                   const ushort_t* __restrict__ Ka,
                                                   const ushort_t* __restrict__ VT,
                                                   ushort_t* __restrict__ O){
  __shared__ __align__(16) ushort_t Ks[64 * 192];   // 24 KB
  __shared__ __align__(16) ushort_t Vs[128 * 64];   // 16 KB  (VT tile: [hd][kv])
  __shared__ __align__(16) ushort_t Ps[4 * 16 * 64];// 8 KB   (per-wave P)
  const int tid = threadIdx.x, lane = tid & 63, wid = tid >> 6;
  const int qb = blockIdx.x, bh = blockIdx.y;
  const int b = bh >> 4, h = bh & 15;
  const int qm0 = qb * 64;
  const int l15 = lane & 15, lhi = lane >> 4;
  const int kf = lhi * 8;
  const float scale = 0.07216878364870323f;         // 1/sqrt(192)

  // Q fragments in registers: 6 k-chunks of 32
  bs8 qf[6];
  const size_t qrow = ((size_t)bh * 2048 + qm0 + wid * 16 + l15) * 192;
#pragma unroll
  for (int kc = 0; kc < 6; ++kc)
    qf[kc] = *(const bs8*)(Qa + qrow + kc * 32 + kf);

  f32x4 acc_o[8] = {};
  float mrow[4] = {-1e30f, -1e30f, -1e30f, -1e30f};
  float lrow[4] = {0.f, 0.f, 0.f, 0.f};

  const ushort_t* Kbh = Ka + (size_t)bh * 2048 * 192;
  const ushort_t* Vbh = VT + (size_t)bh * 128 * 2048;
  ushort_t* Pw = Ps + wid * 16 * 64;

  for (int kt = 0; kt <= qb; ++kt){
    // stage K tile [64][192]: 1536 16B-chunks
#pragma unroll
    for (int i = 0; i < 6; ++i){
      int c = i * 256 + tid;
      gl2lds16(Kbh + (size_t)(kt * 64 + c / 24) * 192 + (c % 24) * 8, Ks + c * 8);
    }
    // stage VT tile [128][64]: 1024 16B-chunks
#pragma unroll
    for (int i = 0; i < 4; ++i){
      int c = i * 256 + tid;
      gl2lds16(Vbh + (size_t)(c >> 3) * 2048 + kt * 64 + (c & 7) * 8, Vs + c * 8);
    }
    __syncthreads();

    // S = Q K^T  (16 q-rows x 64 kv-cols per wave)
    f32x4 s[4] = {};
#pragma unroll
    for (int n = 0; n < 4; ++n)
#pragma unroll
      for (int kc = 0; kc < 6; ++kc){
        bs8 kfr = *(const bs8*)(Ks + (n * 16 + l15) * 192 + kc * 32 + kf);
        s[n] = __builtin_amdgcn_mfma_f32_16x16x32_bf16(qf[kc], kfr, s[n], 0, 0, 0);
      }

    // online softmax (rows = lhi*4+j, cols = n*16+l15)
    float p[4][4];
#pragma unroll
    for (int j = 0; j < 4; ++j){
      const int qi = qm0 + wid * 16 + lhi * 4 + j;
      float rmax = -1e30f;
#pragma unroll
      for (int n = 0; n < 4; ++n){
        int ki = kt * 64 + n * 16 + l15;
        float sv = s[n][j] * scale;
        if (ki > qi) sv = -1e30f;
        p[n][j] = sv;
        rmax = fmaxf(rmax, sv);
      }
      rmax = fmaxf(rmax, __shfl_xor(rmax, 1));
      rmax = fmaxf(rmax, __shfl_xor(rmax, 2));
      rmax = fmaxf(rmax, __shfl_xor(rmax, 4));
      rmax = fmaxf(rmax, __shfl_xor(rmax, 8));
      float mnew = fmaxf(mrow[j], rmax);
      float rsum = 0.f;
#pragma unroll
      for (int n = 0; n < 4; ++n){
        float pv = __expf(p[n][j] - mnew);
        p[n][j] = pv;
        rsum += pv;
      }
      rsum += __shfl_xor(rsum, 1);
      rsum += __shfl_xor(rsum, 2);
      rsum += __shfl_xor(rsum, 4);
      rsum += __shfl_xor(rsum, 8);
      float osc = __expf(mrow[j] - mnew);
      lrow[j] = lrow[j] * osc + rsum;
      mrow[j] = mnew;
#pragma unroll
      for (int f = 0; f < 8; ++f) acc_o[f][j] *= osc;
    }

    // P -> LDS (C/D layout write, A-frag layout read)
#pragma unroll
    for (int j = 0; j < 4; ++j)
#pragma unroll
      for (int n = 0; n < 4; ++n)
        Pw[(lhi * 4 + j) * 64 + n * 16 + l15] = f2bf(p[n][j]);
    __syncthreads();

    // O += P @ V
#pragma unroll
    for (int kc2 = 0; kc2 < 2; ++kc2){
      bs8 pf = *(const bs8*)(Pw + l15 * 64 + kc2 * 32 + kf);
#pragma unroll
      for (int f = 0; f < 8; ++f){
        bs8 vf = *(const bs8*)(Vs + (f * 16 + l15) * 64 + kc2 * 32 + kf);
        acc_o[f] = __builtin_amdgcn_mfma_f32_16x16x32_bf16(pf, vf, acc_o[f], 0, 0, 0);
      }
    }
    __syncthreads();
  }

  // epilogue: divide by l, store to O[M][2048]
#pragma unroll
  for (int f = 0; f < 8; ++f)
#pragma unroll
    for (int j = 0; j < 4; ++j){
      int t = qm0 + wid * 16 + lhi * 4 + j;
      float ov = acc_o[f][j] / lrow[j];
      O[((size_t)b * 2048 + t) * 2048 + h * 128 + f * 16 + l15] = f2bf(ov);
    }
}

extern "C" void kernel_launch(void* const* d_in, const int* in_sizes, int n_in,
                              void* d_out, int out_size, void* d_ws, size_t ws_size,
                              hipStream_t stream){
  constexpr int Bc = 2, Tc = 2048, Cc = 2048, Hc = 16, HDc = 128, RDc = 64, KVRc = 512, QRc = 1024;
  constexpr int Mx = Bc * Tc; // 4096
  const float* x     = (const float*)d_in[0];
  const float* w_dq  = (const float*)d_in[1];
  const float* w_uq  = (const float*)d_in[2];
  const float* w_dkv = (const float*)d_in[3];
  const float* w_uk  = (const float*)d_in[4];
  const float* w_uv  = (const float*)d_in[5];
  const float* w_qr  = (const float*)d_in[6];
  const float* w_kr  = (const float*)d_in[7];
  const float* w_o   = (const float*)d_in[8];
  const float* fc    = (const float*)d_in[9];
  const float* fs    = (const float*)d_in[10];
  float* out = (float*)d_out;

  char* ws = (char*)d_ws;
  size_t off = 0;
  auto alloc = [&](size_t elems) -> ushort_t* {
    ushort_t* p = (ushort_t*)(ws + off);
    off += ((elems * 2) + 255) & ~(size_t)255;
    return p;
  };
  ushort_t* xb    = alloc((size_t)Mx * Cc);
  ushort_t* wdqT  = alloc((size_t)QRc * Cc);
  ushort_t* wuqT  = alloc((size_t)(Hc * HDc) * QRc);
  ushort_t* wdkvT = alloc((size_t)KVRc * Cc);
  ushort_t* wukT  = alloc((size_t)(Hc * HDc) * KVRc);
  ushort_t* wuvT  = alloc((size_t)(Hc * HDc) * KVRc);
  ushort_t* wqrT  = alloc((size_t)(Hc * RDc) * QRc);
  ushort_t* wkrT  = alloc((size_t)(Hc * RDc) * Cc);
  ushort_t* woT   = alloc((size_t)Cc * (Hc * HDc));
  ushort_t* ckv   = alloc((size_t)Mx * KVRc);
  ushort_t* kcb   = alloc((size_t)Mx * Hc * HDc);
  ushort_t* vb    = alloc((size_t)Mx * Hc * HDc);
  ushort_t* cqb   = alloc((size_t)Mx * QRc);
  ushort_t* qcb   = alloc((size_t)Mx * Hc * HDc);
  ushort_t* qrb   = alloc((size_t)Mx * Hc * RDc);
  ushort_t* krb   = alloc((size_t)Mx * Hc * RDc);
  ushort_t* Qa    = alloc((size_t)Bc * Hc * Tc * 192);
  ushort_t* Ka    = alloc((size_t)Bc * Hc * Tc * 192);
  ushort_t* vT    = alloc((size_t)Bc * Hc * HDc * Tc);
  ushort_t* O     = xb;  // alias: xb is dead once the GEMMs consuming it are done

  cast_x<<<dim3(((size_t)Mx * Cc) / 1024), 256, 0, stream>>>(x, xb);

  transpose_cast<<<dim3(QRc / 32, Cc / 32), dim3(32, 8), 0, stream>>>(w_dq, wdqT, Cc, QRc);
  transpose_cast<<<dim3((Hc * HDc) / 32, QRc / 32), dim3(32, 8), 0, stream>>>(w_uq, wuqT, QRc, Hc * HDc);
  transpose_cast<<<dim3(KVRc / 32, Cc / 32), dim3(32, 8), 0, stream>>>(w_dkv, wdkvT, Cc, KVRc);
  transpose_cast<<<dim3((Hc * HDc) / 32, KVRc / 32), dim3(32, 8), 0, stream>>>(w_uk, wukT, KVRc, Hc * HDc);
  transpose_cast<<<dim3((Hc * HDc) / 32, KVRc / 32), dim3(32, 8), 0, stream>>>(w_uv, wuvT, KVRc, Hc * HDc);
  transpose_cast<<<dim3((Hc * RDc) / 32, QRc / 32), dim3(32, 8), 0, stream>>>(w_qr, wqrT, QRc, Hc * RDc);
  transpose_cast<<<dim3((Hc * RDc) / 32, Cc / 32), dim3(32, 8), 0, stream>>>(w_kr, wkrT, Cc, Hc * RDc);
  transpose_cast<<<dim3(Cc / 32, (Hc * HDc) / 32), dim3(32, 8), 0, stream>>>(w_o, woT, Hc * HDc, Cc);

  gemm_bt<ushort_t><<<dim3(Mx / 128, KVRc / 128), 256, 0, stream>>>(xb, wdkvT, ckv, Mx, KVRc, Cc);
  gemm_bt<ushort_t><<<dim3(Mx / 128, (Hc * HDc) / 128), 256, 0, stream>>>(ckv, wukT, kcb, Mx, Hc * HDc, KVRc);
  gemm_bt<ushort_t><<<dim3(Mx / 128, (Hc * HDc) / 128), 256, 0, stream>>>(ckv, wuvT, vb, Mx, Hc * HDc, KVRc);
  gemm_bt<ushort_t><<<dim3(Mx / 128, QRc / 128), 256, 0, stream>>>(xb, wdqT, cqb, Mx, QRc, Cc);
  gemm_bt<ushort_t><<<dim3(Mx / 128, (Hc * HDc) / 128), 256, 0, stream>>>(cqb, wuqT, qcb, Mx, Hc * HDc, QRc);
  gemm_bt<ushort_t><<<dim3(Mx / 128, (Hc * RDc) / 128), 256, 0, stream>>>(cqb, wqrT, qrb, Mx, Hc * RDc, QRc);
  gemm_bt<ushort_t><<<dim3(Mx / 128, (Hc * RDc) / 128), 256, 0, stream>>>(xb, wkrT, krb, Mx, Hc * RDc, Cc);

  assemble_qk<<<Mx, 256, 0, stream>>>(qcb, qrb, fc, fs, Qa);
  assemble_qk<<<Mx, 256, 0, stream>>>(kcb, krb, fc, fs, Ka);
  transpose_v<<<dim3(Tc / 32, HDc / 32, Bc * Hc), dim3(32, 8), 0, stream>>>(vb, vT);

  attn_kernel<<<dim3(Tc / 64, Bc * Hc), 256, 0, stream>>>(Qa, Ka, vT, O);

  gemm_bt<float><<<dim3(Mx / 128, Cc / 128), 256, 0, stream>>>(O, woT, out, Mx, Cc, Hc * HDc);
}

// Round 2
// 433.770 us; speedup vs baseline: 1.4378x; 1.4378x over previous
//
#include <hip/hip_runtime.h>

typedef unsigned short ushort_t;
typedef __attribute__((ext_vector_type(8))) short bs8;       // 8 x bf16 (4 VGPR)
typedef __attribute__((ext_vector_type(4))) float f32x4;
typedef __attribute__((ext_vector_type(4))) unsigned short u16x4;

#define DEV __device__ __forceinline__

DEV unsigned short f2bf(float f){
  unsigned u = __float_as_uint(f);
  u += 0x7fffu + ((u >> 16) & 1u);           // round-to-nearest-even
  return (unsigned short)(u >> 16);
}
DEV float bf2f(unsigned short h){ return __uint_as_float(((unsigned)h) << 16); }

DEV void gl2lds16(const void* g, void* l){
  __builtin_amdgcn_global_load_lds((const __attribute__((address_space(1))) void*)g,
                                   (__attribute__((address_space(3))) void*)l, 16, 0, 0);
}

DEV void st_out(ushort_t* C, size_t i, float v){ C[i] = f2bf(v); }
DEV void st_out(float*    C, size_t i, float v){ C[i] = v; }

// ---------------- cast x (fp32 -> bf16), 4 elems/thread ----------------
__global__ __launch_bounds__(256) void cast_x(const float* __restrict__ in,
                                              ushort_t* __restrict__ outb){
  size_t i = ((size_t)blockIdx.x * 256 + threadIdx.x) * 4;
  float4 v = *(const float4*)(in + i);
  u16x4 o;
  o[0] = f2bf(v.x); o[1] = f2bf(v.y); o[2] = f2bf(v.z); o[3] = f2bf(v.w);
  *(u16x4*)(outb + i) = o;
}

// ---------------- transpose-cast weight: in[K][N] fp32 -> out[N][K] bf16 ----------------
__global__ __launch_bounds__(256) void transpose_cast(const float* __restrict__ in,
                                                      ushort_t* __restrict__ out,
                                                      int K, int N){
  __shared__ float tile[32][33];
  int k0 = blockIdx.y * 32, n0 = blockIdx.x * 32;
  int tx = threadIdx.x, ty = threadIdx.y;
  for (int r = ty; r < 32; r += 8)
    tile[r][tx] = in[(size_t)(k0 + r) * N + n0 + tx];
  __syncthreads();
  for (int r = ty; r < 32; r += 8)
    out[(size_t)(n0 + r) * K + k0 + tx] = f2bf(tile[tx][r]);
}

// ---------------- bf16 transpose per (b,h): v[M][ldv] (cols voff..) -> vT[BH][128][T] ----------------
__global__ __launch_bounds__(256) void transpose_v(const ushort_t* __restrict__ v, int ldv,
                                                   ushort_t* __restrict__ vT){
  __shared__ ushort_t tile[32][33];
  int bh = blockIdx.z; int b = bh >> 4, h = bh & 15;
  int t0 = blockIdx.x * 32, d0 = blockIdx.y * 32;
  int tx = threadIdx.x, ty = threadIdx.y;
  for (int r = ty; r < 32; r += 8)
    tile[r][tx] = v[((size_t)(b * 2048 + t0 + r)) * ldv + h * 128 + d0 + tx];
  __syncthreads();
  for (int r = ty; r < 32; r += 8)
    vT[((size_t)bh * 128 + d0 + r) * 2048 + t0 + tx] = tile[tx][r];
}

// ---------------- assemble Q or K: concat core[M][.] + rope(rot[M][.]) -> [BH][T][192] ----------------
__global__ __launch_bounds__(256) void assemble_qk(const ushort_t* __restrict__ core, int cs,
                                                   const ushort_t* __restrict__ rot, int rs,
                                                   const float* __restrict__ fc,
                                                   const float* __restrict__ fs,
                                                   ushort_t* __restrict__ outb){
  const int m = blockIdx.x;
  const int b = m >> 11, t = m & 2047;
  for (int i = threadIdx.x; i < 2048; i += 256){
    int h = i >> 7, d = i & 127;
    outb[((size_t)(b * 16 + h) * 2048 + t) * 192 + d] = core[(size_t)m * cs + i];
  }
  for (int p = threadIdx.x; p < 512; p += 256){
    int h = p >> 5, i = p & 31;
    float tr = bf2f(rot[(size_t)m * rs + h * 64 + 2 * i]);
    float ti = bf2f(rot[(size_t)m * rs + h * 64 + 2 * i + 1]);
    float c = fc[t * 32 + i], s = fs[t * 32 + i];
    size_t base = ((size_t)(b * 16 + h) * 2048 + t) * 192 + 128;
    outb[base + 2 * i]     = f2bf(tr * c - ti * s);
    outb[base + 2 * i + 1] = f2bf(tr * s + ti * c);
  }
}

// ---------------- GEMM: C[M][N] = A[M][K](lda) @ BT[N][K]^T   (m97-style 128x128, BK=32) ----------------
template<typename OT>
__global__ __launch_bounds__(256) void gemm_bt(const ushort_t* __restrict__ A, int lda,
                                               const ushort_t* __restrict__ BT,
                                               OT* __restrict__ C,
                                               int M, int N, int K){
  __shared__ __align__(16) ushort_t As[128 * 32];
  __shared__ __align__(16) ushort_t Bs[128 * 32];
  const int tid = threadIdx.x;
  const int lane = tid & 63;
  const int wid = tid >> 6;
  const int l15 = lane & 15;
  const int kf = (lane >> 4) * 8;
  const int m0 = blockIdx.x * 128;
  const int n0 = blockIdx.y * 128;
  const int wr = wid >> 1, wc = wid & 1;

  const int c0 = tid, c1 = tid + 256;           // 16B chunks: row=c>>2, col8=(c&3)*8
  const ushort_t* a0 = A + (size_t)(m0 + (c0 >> 2)) * lda + (c0 & 3) * 8;
  const ushort_t* a1 = A + (size_t)(m0 + (c1 >> 2)) * lda + (c1 & 3) * 8;
  const ushort_t* b0 = BT + (size_t)(n0 + (c0 >> 2)) * K + (c0 & 3) * 8;
  const ushort_t* b1 = BT + (size_t)(n0 + (c1 >> 2)) * K + (c1 & 3) * 8;
  ushort_t* la0 = As + c0 * 8;
  ushort_t* la1 = As + c1 * 8;
  ushort_t* lb0 = Bs + c0 * 8;
  ushort_t* lb1 = Bs + c1 * 8;

  f32x4 acc[4][4] = {};

  for (int k0 = 0; k0 < K; k0 += 32){
    gl2lds16(a0 + k0, la0);
    gl2lds16(a1 + k0, la1);
    gl2lds16(b0 + k0, lb0);
    gl2lds16(b1 + k0, lb1);
    __syncthreads();
    bs8 af[4], bfv[4];
#pragma unroll
    for (int m = 0; m < 4; ++m)
      af[m] = *(const bs8*)(As + (wr * 64 + m * 16 + l15) * 32 + kf);
#pragma unroll
    for (int n = 0; n < 4; ++n)
      bfv[n] = *(const bs8*)(Bs + (wc * 64 + n * 16 + l15) * 32 + kf);
#pragma unroll
    for (int m = 0; m < 4; ++m)
#pragma unroll
      for (int n = 0; n < 4; ++n)
        acc[m][n] = __builtin_amdgcn_mfma_f32_16x16x32_bf16(af[m], bfv[n], acc[m][n], 0, 0, 0);
    __syncthreads();
  }

#pragma unroll
  for (int m = 0; m < 4; ++m){
    const int r0 = m0 + wr * 64 + m * 16 + (lane >> 4) * 4;
#pragma unroll
    for (int n = 0; n < 4; ++n){
      const int cc = n0 + wc * 64 + n * 16 + l15;
#pragma unroll
      for (int j = 0; j < 4; ++j)
        st_out(C, (size_t)(r0 + j) * N + cc, acc[m][n][j]);
    }
  }
}

// ---------------- flash attention v2: QB=128, 8 waves, XOR-swizzled LDS ----------------
// Q[BH][T][192], K[BH][T][192], VT[BH][128][T] -> O[M][2048]
__global__ __launch_bounds__(512, 4) void attn_kernel(const ushort_t* __restrict__ Qa,
                                                      const ushort_t* __restrict__ Ka,
                                                      const ushort_t* __restrict__ VT,
                                                      ushort_t* __restrict__ O){
  __shared__ __align__(16) ushort_t Ks[64 * 192];    // 24 KB (16B-chunk-swizzled)
  __shared__ __align__(16) ushort_t Vs[128 * 64];    // 16 KB (16B-chunk-swizzled)
  __shared__ __align__(16) ushort_t Ps[8 * 16 * 64]; // 16 KB (per-wave P, swizzled)
  const int tid = threadIdx.x, lane = tid & 63, wid = tid >> 6;
  const int bh = blockIdx.x;
  const int yy = blockIdx.y;
  const int qb = (yy < 8) ? (15 - yy) : (yy - 8);    // pair big+small per CU (round-robin)
  const int b = bh >> 4, h = bh & 15;
  const int qm0 = qb * 128;
  const int l15 = lane & 15, lhi = lane >> 4;
  const int kf = lhi * 8;
  const int sw = l15 & 7;                            // row&7 for all swizzled reads
  const float scale = 0.07216878364870323f;          // 1/sqrt(192)

  // Q fragments in registers: 6 k-chunks of 32 (16 q-rows per wave)
  bs8 qf[6];
  const size_t qrow = ((size_t)bh * 2048 + qm0 + wid * 16 + l15) * 192;
#pragma unroll
  for (int kc = 0; kc < 6; ++kc)
    qf[kc] = *(const bs8*)(Qa + qrow + kc * 32 + kf);

  f32x4 acc_o[8] = {};
  float mrow[4] = {-1e30f, -1e30f, -1e30f, -1e30f};
  float lrow[4] = {0.f, 0.f, 0.f, 0.f};

  const ushort_t* Kbh = Ka + (size_t)bh * 2048 * 192;
  const ushort_t* Vbh = VT + (size_t)bh * 128 * 2048;
  ushort_t* Pw = Ps + wid * 16 * 64;

  // Precompute swizzled staging sources (kt-invariant parts).
  // K: 1536 chunks of 16B; chunk c -> LDS elem c*8; row=c/24, col16=c%24;
  //    global col16 = col16 ^ (row&7)  (inverse-swizzled source, rule #21)
  const ushort_t* ksrc[3];
  ushort_t* kdst[3];
#pragma unroll
  for (int i = 0; i < 3; ++i){
    int c = i * 512 + tid;
    int row = c / 24, col = c % 24;
    ksrc[i] = Kbh + (size_t)row * 192 + (col ^ (row & 7)) * 8;
    kdst[i] = Ks + c * 8;
  }
  // V: 1024 chunks; row=d=c/8, col16=c%8
  const ushort_t* vsrc[2];
  ushort_t* vdst[2];
#pragma unroll
  for (int i = 0; i < 2; ++i){
    int c = i * 512 + tid;
    int d = c >> 3, col = c & 7;
    vsrc[i] = Vbh + (size_t)d * 2048 + (col ^ (d & 7)) * 8;
    vdst[i] = Vs + c * 8;
  }

  const int nkt = 2 * qb + 2;
  const int mylast = (qm0 + wid * 16 + 15) >> 6;     // last kt with any unmasked col

  for (int kt = 0; kt < nkt; ++kt){
#pragma unroll
    for (int i = 0; i < 3; ++i) gl2lds16(ksrc[i] + (size_t)kt * 64 * 192, kdst[i]);
#pragma unroll
    for (int i = 0; i < 2; ++i) gl2lds16(vsrc[i] + kt * 64, vdst[i]);
    __syncthreads();

    if (kt <= mylast){
      // S = Q K^T  (16 q-rows x 64 kv-cols per wave); K row&7 == sw
      f32x4 s[4] = {};
#pragma unroll
      for (int n = 0; n < 4; ++n)
#pragma unroll
        for (int kc = 0; kc < 6; ++kc){
          bs8 kfr = *(const bs8*)(Ks + (n * 16 + l15) * 192 + (((kc * 4 + lhi) ^ sw) << 3));
          s[n] = __builtin_amdgcn_mfma_f32_16x16x32_bf16(qf[kc], kfr, s[n], 0, 0, 0);
        }

      // online softmax (rows = lhi*4+j, cols = n*16+l15)
      float p[4][4];
#pragma unroll
      for (int j = 0; j < 4; ++j){
        const int qi = qm0 + wid * 16 + lhi * 4 + j;
        float rmax = -1e30f;
#pragma unroll
        for (int n = 0; n < 4; ++n){
          int ki = kt * 64 + n * 16 + l15;
          float sv = s[n][j] * scale;
          if (ki > qi) sv = -1e30f;
          p[n][j] = sv;
          rmax = fmaxf(rmax, sv);
        }
        rmax = fmaxf(rmax, __shfl_xor(rmax, 1));
        rmax = fmaxf(rmax, __shfl_xor(rmax, 2));
        rmax = fmaxf(rmax, __shfl_xor(rmax, 4));
        rmax = fmaxf(rmax, __shfl_xor(rmax, 8));
        float mnew = fmaxf(mrow[j], rmax);
        float rsum = 0.f;
#pragma unroll
        for (int n = 0; n < 4; ++n){
          float pv = __expf(p[n][j] - mnew);
          p[n][j] = pv;
          rsum += pv;
        }
        rsum += __shfl_xor(rsum, 1);
        rsum += __shfl_xor(rsum, 2);
        rsum += __shfl_xor(rsum, 4);
        rsum += __shfl_xor(rsum, 8);
        float osc = __expf(mrow[j] - mnew);
        lrow[j] = lrow[j] * osc + rsum;
        mrow[j] = mnew;
#pragma unroll
        for (int f = 0; f < 8; ++f) acc_o[f][j] *= osc;
      }

      // P -> per-wave LDS, element-swizzled (col ^ ((row&7)<<3))
#pragma unroll
      for (int j = 0; j < 4; ++j){
        const int prow = lhi * 4 + j;
#pragma unroll
        for (int n = 0; n < 4; ++n)
          Pw[prow * 64 + ((n * 16 + l15) ^ ((prow & 7) << 3))] = f2bf(p[n][j]);
      }
      // (no barrier: P is private to this wave; compiler orders LDS ops)

      // O += P @ V  (P row&7 == sw, V row&7 == sw)
#pragma unroll
      for (int kc2 = 0; kc2 < 2; ++kc2){
        bs8 pf = *(const bs8*)(Pw + l15 * 64 + (((kc2 * 4 + lhi) ^ sw) << 3));
#pragma unroll
        for (int f = 0; f < 8; ++f){
          bs8 vf = *(const bs8*)(Vs + (f * 16 + l15) * 64 + (((kc2 * 4 + lhi) ^ sw) << 3));
          acc_o[f] = __builtin_amdgcn_mfma_f32_16x16x32_bf16(pf, vf, acc_o[f], 0, 0, 0);
        }
      }
    }
    __syncthreads();
  }

  // epilogue: divide by l, store to O[M][2048]
#pragma unroll
  for (int f = 0; f < 8; ++f)
#pragma unroll
    for (int j = 0; j < 4; ++j){
      int t = qm0 + wid * 16 + lhi * 4 + j;
      float ov = acc_o[f][j] / lrow[j];
      O[((size_t)b * 2048 + t) * 2048 + h * 128 + f * 16 + l15] = f2bf(ov);
    }
}

extern "C" void kernel_launch(void* const* d_in, const int* in_sizes, int n_in,
                              void* d_out, int out_size, void* d_ws, size_t ws_size,
                              hipStream_t stream){
  constexpr int Bc = 2, Tc = 2048, Cc = 2048, Hc = 16, HDc = 128, RDc = 64, KVRc = 512, QRc = 1024;
  constexpr int Mx = Bc * Tc; // 4096
  const float* x     = (const float*)d_in[0];
  const float* w_dq  = (const float*)d_in[1];
  const float* w_uq  = (const float*)d_in[2];
  const float* w_dkv = (const float*)d_in[3];
  const float* w_uk  = (const float*)d_in[4];
  const float* w_uv  = (const float*)d_in[5];
  const float* w_qr  = (const float*)d_in[6];
  const float* w_kr  = (const float*)d_in[7];
  const float* w_o   = (const float*)d_in[8];
  const float* fc    = (const float*)d_in[9];
  const float* fs    = (const float*)d_in[10];
  float* out = (float*)d_out;

  char* ws = (char*)d_ws;
  size_t off = 0;
  auto alloc = [&](size_t elems) -> ushort_t* {
    ushort_t* p = (ushort_t*)(ws + off);
    off += ((elems * 2) + 255) & ~(size_t)255;
    return p;
  };
  ushort_t* xb    = alloc((size_t)Mx * Cc);
  // BT1 group (adjacent, N-order): [cq 1024 | ckv 512 | kr 1024], K=2048
  ushort_t* wdqT  = alloc((size_t)QRc * Cc);
  ushort_t* wdkvT = alloc((size_t)KVRc * Cc);
  ushort_t* wkrT  = alloc((size_t)(Hc * RDc) * Cc);
  // BT2 group: [qc 2048 | qr 1024], K=1024
  ushort_t* wuqT  = alloc((size_t)(Hc * HDc) * QRc);
  ushort_t* wqrT  = alloc((size_t)(Hc * RDc) * QRc);
  // BT3 group: [kc 2048 | v 2048], K=512
  ushort_t* wukT  = alloc((size_t)(Hc * HDc) * KVRc);
  ushort_t* wuvT  = alloc((size_t)(Hc * HDc) * KVRc);
  ushort_t* woT   = alloc((size_t)Cc * (Hc * HDc));
  ushort_t* comb1 = alloc((size_t)Mx * 2560);   // [cq | ckv | kr]
  ushort_t* qcomb = alloc((size_t)Mx * 3072);   // [qc | qr]
  ushort_t* kvcomb= alloc((size_t)Mx * 4096);   // [kc | v]
  ushort_t* Qa    = alloc((size_t)Bc * Hc * Tc * 192);
  ushort_t* Ka    = alloc((size_t)Bc * Hc * Tc * 192);
  ushort_t* vT    = alloc((size_t)Bc * Hc * HDc * Tc);
  ushort_t* O     = xb;  // alias: xb dead after GEMM1

  cast_x<<<dim3(((size_t)Mx * Cc) / 1024), 256, 0, stream>>>(x, xb);

  transpose_cast<<<dim3(QRc / 32, Cc / 32), dim3(32, 8), 0, stream>>>(w_dq, wdqT, Cc, QRc);
  transpose_cast<<<dim3(KVRc / 32, Cc / 32), dim3(32, 8), 0, stream>>>(w_dkv, wdkvT, Cc, KVRc);
  transpose_cast<<<dim3((Hc * RDc) / 32, Cc / 32), dim3(32, 8), 0, stream>>>(w_kr, wkrT, Cc, Hc * RDc);
  transpose_cast<<<dim3((Hc * HDc) / 32, QRc / 32), dim3(32, 8), 0, stream>>>(w_uq, wuqT, QRc, Hc * HDc);
  transpose_cast<<<dim3((Hc * RDc) / 32, QRc / 32), dim3(32, 8), 0, stream>>>(w_qr, wqrT, QRc, Hc * RDc);
  transpose_cast<<<dim3((Hc * HDc) / 32, KVRc / 32), dim3(32, 8), 0, stream>>>(w_uk, wukT, KVRc, Hc * HDc);
  transpose_cast<<<dim3((Hc * HDc) / 32, KVRc / 32), dim3(32, 8), 0, stream>>>(w_uv, wuvT, KVRc, Hc * HDc);
  transpose_cast<<<dim3(Cc / 32, (Hc * HDc) / 32), dim3(32, 8), 0, stream>>>(w_o, woT, Hc * HDc, Cc);

  // GEMM1: x @ [w_dq | w_dkv | w_kr]  -> comb1 [4096][2560]
  gemm_bt<ushort_t><<<dim3(Mx / 128, 2560 / 128), 256, 0, stream>>>(xb, Cc, wdqT, comb1, Mx, 2560, Cc);
  // GEMM2: cq @ [w_uq | w_qr] -> qcomb [4096][3072]
  gemm_bt<ushort_t><<<dim3(Mx / 128, 3072 / 128), 256, 0, stream>>>(comb1, 2560, wuqT, qcomb, Mx, 3072, QRc);
  // GEMM3: ckv @ [w_uk | w_uv] -> kvcomb [4096][4096]
  gemm_bt<ushort_t><<<dim3(Mx / 128, 4096 / 128), 256, 0, stream>>>(comb1 + QRc, 2560, wukT, kvcomb, Mx, 4096, KVRc);

  assemble_qk<<<Mx, 256, 0, stream>>>(qcomb, 3072, qcomb + 2048, 3072, fc, fs, Qa);
  assemble_qk<<<Mx, 256, 0, stream>>>(kvcomb, 4096, comb1 + 1536, 2560, fc, fs, Ka);
  transpose_v<<<dim3(Tc / 32, HDc / 32, Bc * Hc), dim3(32, 8), 0, stream>>>(kvcomb + 2048, 4096, vT);

  attn_kernel<<<dim3(Bc * Hc, 16), 512, 0, stream>>>(Qa, Ka, vT, O);

  gemm_bt<float><<<dim3(Mx / 128, Cc / 128), 256, 0, stream>>>(O, Hc * HDc, woT, out, Mx, Cc, Hc * HDc);
}

// Round 3
// 409.792 us; speedup vs baseline: 1.5219x; 1.0585x over previous
//
#include <hip/hip_runtime.h>

typedef unsigned short ushort_t;
typedef __attribute__((ext_vector_type(8))) short bs8;       // 8 x bf16 (4 VGPR)
typedef __attribute__((ext_vector_type(4))) float f32x4;
typedef __attribute__((ext_vector_type(4))) unsigned short u16x4;

#define DEV __device__ __forceinline__

DEV unsigned short f2bf(float f){
  unsigned u = __float_as_uint(f);
  u += 0x7fffu + ((u >> 16) & 1u);           // round-to-nearest-even
  return (unsigned short)(u >> 16);
}
DEV float bf2f(unsigned short h){ return __uint_as_float(((unsigned)h) << 16); }

DEV void gl2lds16(const void* g, void* l){
  __builtin_amdgcn_global_load_lds((const __attribute__((address_space(1))) void*)g,
                                   (__attribute__((address_space(3))) void*)l, 16, 0, 0);
}

DEV void st_out(ushort_t* C, size_t i, float v){ C[i] = f2bf(v); }
DEV void st_out(float*    C, size_t i, float v){ C[i] = v; }

// ---------------- cast x (fp32 -> bf16), 4 elems/thread ----------------
__global__ __launch_bounds__(256) void cast_x(const float* __restrict__ in,
                                              ushort_t* __restrict__ outb){
  size_t i = ((size_t)blockIdx.x * 256 + threadIdx.x) * 4;
  float4 v = *(const float4*)(in + i);
  u16x4 o;
  o[0] = f2bf(v.x); o[1] = f2bf(v.y); o[2] = f2bf(v.z); o[3] = f2bf(v.w);
  *(u16x4*)(outb + i) = o;
}

// ---------------- transpose-cast weight: in[K][N] fp32 -> out[N][K] bf16 ----------------
__global__ __launch_bounds__(256) void transpose_cast(const float* __restrict__ in,
                                                      ushort_t* __restrict__ out,
                                                      int K, int N){
  __shared__ float tile[32][33];
  int k0 = blockIdx.y * 32, n0 = blockIdx.x * 32;
  int tx = threadIdx.x, ty = threadIdx.y;
  for (int r = ty; r < 32; r += 8)
    tile[r][tx] = in[(size_t)(k0 + r) * N + n0 + tx];
  __syncthreads();
  for (int r = ty; r < 32; r += 8)
    out[(size_t)(n0 + r) * K + k0 + tx] = f2bf(tile[tx][r]);
}

// ---------------- bf16 transpose per (b,h): v[M][ldv] -> vT[BH][128][T] ----------------
__global__ __launch_bounds__(256) void transpose_v(const ushort_t* __restrict__ v, int ldv,
                                                   ushort_t* __restrict__ vT){
  __shared__ ushort_t tile[32][33];
  int bh = blockIdx.z; int b = bh >> 4, h = bh & 15;
  int t0 = blockIdx.x * 32, d0 = blockIdx.y * 32;
  int tx = threadIdx.x, ty = threadIdx.y;
  for (int r = ty; r < 32; r += 8)
    tile[r][tx] = v[((size_t)(b * 2048 + t0 + r)) * ldv + h * 128 + d0 + tx];
  __syncthreads();
  for (int r = ty; r < 32; r += 8)
    vT[((size_t)bh * 128 + d0 + r) * 2048 + t0 + tx] = tile[tx][r];
}

// ---------------- assemble Q or K: concat core[M][.] + rope(rot[M][.]) -> [BH][T][192] ----------------
__global__ __launch_bounds__(256) void assemble_qk(const ushort_t* __restrict__ core, int cs,
                                                   const ushort_t* __restrict__ rot, int rs,
                                                   const float* __restrict__ fc,
                                                   const float* __restrict__ fs,
                                                   ushort_t* __restrict__ outb){
  const int m = blockIdx.x;
  const int b = m >> 11, t = m & 2047;
  for (int i = threadIdx.x; i < 2048; i += 256){
    int h = i >> 7, d = i & 127;
    outb[((size_t)(b * 16 + h) * 2048 + t) * 192 + d] = core[(size_t)m * cs + i];
  }
  for (int p = threadIdx.x; p < 512; p += 256){
    int h = p >> 5, i = p & 31;
    float tr = bf2f(rot[(size_t)m * rs + h * 64 + 2 * i]);
    float ti = bf2f(rot[(size_t)m * rs + h * 64 + 2 * i + 1]);
    float c = fc[t * 32 + i], s = fs[t * 32 + i];
    size_t base = ((size_t)(b * 16 + h) * 2048 + t) * 192 + 128;
    outb[base + 2 * i]     = f2bf(tr * c - ti * s);
    outb[base + 2 * i + 1] = f2bf(tr * s + ti * c);
  }
}

// ================= 256x256 8-phase GEMM (T2+T3+T4+T5), BK=64 =================
// C[M][N] = A[M][K](lda) @ BT[N][K]^T. 512 thr = 8 waves (2M x 4N), per-wave 128x64.
// LDS 128 KiB: [buf(2)][region: A0,A1,B0,B1][128 rows][64 cols] bf16, chunk-XOR swizzled.
template<typename OT>
__global__ __launch_bounds__(512, 2) void gemm256(const ushort_t* __restrict__ A, int lda,
                                                  const ushort_t* __restrict__ BT,
                                                  OT* __restrict__ C,
                                                  int M, int N, int K){
  __shared__ __align__(16) ushort_t lds[65536];   // 128 KiB
  const int tid = threadIdx.x, lane = tid & 63, wid = tid >> 6;
  const int l15 = lane & 15, lhi = lane >> 4;
  const int wr = wid >> 2, wc = wid & 3;

  // bijective XCD swizzle (all our grids have nwg % 8 == 0)
  const int nbx = M >> 8;
  const int nwg = gridDim.x;
  const int orig = blockIdx.x;
  const int wg = (orig & 7) * (nwg >> 3) + (orig >> 3);
  const int m0 = (wg % nbx) << 8;
  const int n0 = (wg / nbx) << 8;

  // staging: half-tile = 128 rows x 8 chunks(16B); thread t covers chunks t and 512+t
  const int trow = tid >> 3;                       // 0..63 (+ i*64)
  const int tcsrc = (tid & 7) ^ (trow & 7);        // inverse-swizzled source chunk
  const ushort_t* gA[2][2];
  const ushort_t* gB[2][2];
#pragma unroll
  for (int h = 0; h < 2; ++h)
#pragma unroll
    for (int i = 0; i < 2; ++i){
      gA[h][i] = A  + (size_t)(m0 + h * 128 + i * 64 + trow) * lda + tcsrc * 8;
      gB[h][i] = BT + (size_t)(n0 + h * 128 + i * 64 + trow) * K   + tcsrc * 8;
    }

  auto STAGE_A = [&](int buf, int h, int kt){
    gl2lds16(gA[h][0] + (size_t)kt * 64, lds + buf * 32768 + h * 8192 + tid * 8);
    gl2lds16(gA[h][1] + (size_t)kt * 64, lds + buf * 32768 + h * 8192 + 4096 + tid * 8);
  };
  auto STAGE_B = [&](int buf, int h, int kt){
    gl2lds16(gB[h][0] + (size_t)kt * 64, lds + buf * 32768 + 16384 + h * 8192 + tid * 8);
    gl2lds16(gB[h][1] + (size_t)kt * 64, lds + buf * 32768 + 16384 + h * 8192 + 4096 + tid * 8);
  };

  // fragment read chunk offsets (elements): chunk = (ks*4+lhi) ^ (row&7), row&7 == l15&7
  const int ck0 = ((lhi) ^ (l15 & 7)) << 3;
  const int ck1 = ((4 + lhi) ^ (l15 & 7)) << 3;

  f32x4 acc[8][4] = {};
  bs8 aF[4][2], bLo[2][2], bHi[2][2];

  auto RDA = [&](int buf, int mq){
#pragma unroll
    for (int m = 0; m < 4; ++m){
      const ushort_t* r = lds + buf * 32768 + wr * 8192 + ((mq + m) * 16 + l15) * 64;
      aF[m][0] = *(const bs8*)(r + ck0);
      aF[m][1] = *(const bs8*)(r + ck1);
    }
  };
  auto RDB = [&](int buf, int nq, bs8 (&br)[2][2]){
#pragma unroll
    for (int n = 0; n < 2; ++n){
      const ushort_t* r = lds + buf * 32768 + 16384 + (wc >> 1) * 8192 +
                          ((wc & 1) * 64 + (nq + n) * 16 + l15) * 64;
      br[n][0] = *(const bs8*)(r + ck0);
      br[n][1] = *(const bs8*)(r + ck1);
    }
  };
  auto MMA = [&](int mq, int nq, bs8 (&br)[2][2]){
    __builtin_amdgcn_s_setprio(1);
#pragma unroll
    for (int m = 0; m < 4; ++m)
#pragma unroll
      for (int n = 0; n < 2; ++n){
        acc[mq + m][nq + n] = __builtin_amdgcn_mfma_f32_16x16x32_bf16(aF[m][0], br[n][0], acc[mq + m][nq + n], 0, 0, 0);
        acc[mq + m][nq + n] = __builtin_amdgcn_mfma_f32_16x16x32_bf16(aF[m][1], br[n][1], acc[mq + m][nq + n], 0, 0, 0);
      }
    __builtin_amdgcn_s_setprio(0);
  };

#define BAR() __builtin_amdgcn_s_barrier()
#define LGK() asm volatile("s_waitcnt lgkmcnt(0)" ::: "memory")
#define VMC4() asm volatile("s_waitcnt vmcnt(4)" ::: "memory")

  const int nkt = K >> 6;
  const int nIter = K >> 7;

  // prologue: kt0 full (buf0) + kt1's B (buf1); kt1's A comes at ph1/ph2
  STAGE_A(0, 0, 0); STAGE_A(0, 1, 0); STAGE_B(0, 0, 0); STAGE_B(0, 1, 0);
  STAGE_B(1, 0, 1); STAGE_B(1, 1, 1);
  VMC4();                                   // kt0 fully landed (kt1's B may be in flight)
  BAR();

  for (int it = 0; it < nIter; ++it){
    const int kt1 = 2 * it + 1;
    int kt2 = 2 * it + 2; if (kt2 > nkt - 1) kt2 = nkt - 1;
    int kt3 = 2 * it + 3; if (kt3 > nkt - 1) kt3 = nkt - 1;
    // ph1
    RDA(0, 0); RDB(0, 0, bLo);
    STAGE_A(1, 0, kt1);
    BAR(); LGK(); MMA(0, 0, bLo); BAR();
    // ph2
    RDB(0, 2, bHi);
    STAGE_A(1, 1, kt1);
    BAR(); LGK(); MMA(0, 2, bHi); BAR();
    // ph3
    RDA(0, 4);
    STAGE_B(0, 0, kt2);
    BAR(); LGK(); MMA(4, 0, bLo); BAR();
    // ph4
    STAGE_B(0, 1, kt2);
    BAR(); LGK(); MMA(4, 2, bHi);
    VMC4(); BAR();
    // ph5
    RDA(1, 0); RDB(1, 0, bLo);
    STAGE_A(0, 0, kt2);
    BAR(); LGK(); MMA(0, 0, bLo); BAR();
    // ph6
    RDB(1, 2, bHi);
    STAGE_A(0, 1, kt2);
    BAR(); LGK(); MMA(0, 2, bHi); BAR();
    // ph7
    RDA(1, 4);
    STAGE_B(1, 0, kt3);
    BAR(); LGK(); MMA(4, 0, bLo); BAR();
    // ph8
    STAGE_B(1, 1, kt3);
    BAR(); LGK(); MMA(4, 2, bHi);
    VMC4(); BAR();
  }
#undef BAR
#undef LGK
#undef VMC4

  // epilogue
#pragma unroll
  for (int m = 0; m < 8; ++m){
    const int r = m0 + wr * 128 + m * 16 + lhi * 4;
#pragma unroll
    for (int n = 0; n < 4; ++n){
      const int c = n0 + wc * 64 + n * 16 + l15;
#pragma unroll
      for (int j = 0; j < 4; ++j)
        st_out(C, (size_t)(r + j) * N + c, acc[m][n][j]);
    }
  }
}

// ---------------- flash attention: QB=128, 8 waves, XOR-swizzled LDS ----------------
__global__ __launch_bounds__(512, 4) void attn_kernel(const ushort_t* __restrict__ Qa,
                                                      const ushort_t* __restrict__ Ka,
                                                      const ushort_t* __restrict__ VT,
                                                      ushort_t* __restrict__ O){
  __shared__ __align__(16) ushort_t Ks[64 * 192];
  __shared__ __align__(16) ushort_t Vs[128 * 64];
  __shared__ __align__(16) ushort_t Ps[8 * 16 * 64];
  const int tid = threadIdx.x, lane = tid & 63, wid = tid >> 6;
  const int bh = blockIdx.x;
  const int yy = blockIdx.y;
  const int qb = (yy < 8) ? (15 - yy) : (yy - 8);
  const int b = bh >> 4, h = bh & 15;
  const int qm0 = qb * 128;
  const int l15 = lane & 15, lhi = lane >> 4;
  const int kf = lhi * 8;
  const int sw = l15 & 7;
  const float scale2 = 0.07216878364870323f * 1.4426950408889634f; // 1/sqrt(192)*log2e

  bs8 qf[6];
  const size_t qrow = ((size_t)bh * 2048 + qm0 + wid * 16 + l15) * 192;
#pragma unroll
  for (int kc = 0; kc < 6; ++kc)
    qf[kc] = *(const bs8*)(Qa + qrow + kc * 32 + kf);

  f32x4 acc_o[8] = {};
  float mrow[4] = {-1e30f, -1e30f, -1e30f, -1e30f};
  float lrow[4] = {0.f, 0.f, 0.f, 0.f};

  const ushort_t* Kbh = Ka + (size_t)bh * 2048 * 192;
  const ushort_t* Vbh = VT + (size_t)bh * 128 * 2048;
  ushort_t* Pw = Ps + wid * 16 * 64;

  const ushort_t* ksrc[3];
  ushort_t* kdst[3];
#pragma unroll
  for (int i = 0; i < 3; ++i){
    int c = i * 512 + tid;
    int row = c / 24, col = c % 24;
    ksrc[i] = Kbh + (size_t)row * 192 + (col ^ (row & 7)) * 8;
    kdst[i] = Ks + c * 8;
  }
  const ushort_t* vsrc[2];
  ushort_t* vdst[2];
#pragma unroll
  for (int i = 0; i < 2; ++i){
    int c = i * 512 + tid;
    int d = c >> 3, col = c & 7;
    vsrc[i] = Vbh + (size_t)d * 2048 + (col ^ (d & 7)) * 8;
    vdst[i] = Vs + c * 8;
  }

  const int nkt = 2 * qb + 2;
  const int mylast = (qm0 + wid * 16 + 15) >> 6;

  for (int kt = 0; kt < nkt; ++kt){
#pragma unroll
    for (int i = 0; i < 3; ++i) gl2lds16(ksrc[i] + (size_t)kt * 64 * 192, kdst[i]);
#pragma unroll
    for (int i = 0; i < 2; ++i) gl2lds16(vsrc[i] + kt * 64, vdst[i]);
    __syncthreads();

    if (kt <= mylast){
      f32x4 s[4] = {};
#pragma unroll
      for (int n = 0; n < 4; ++n)
#pragma unroll
        for (int kc = 0; kc < 6; ++kc){
          bs8 kfr = *(const bs8*)(Ks + (n * 16 + l15) * 192 + (((kc * 4 + lhi) ^ sw) << 3));
          s[n] = __builtin_amdgcn_mfma_f32_16x16x32_bf16(qf[kc], kfr, s[n], 0, 0, 0);
        }

      // online softmax in log2 domain, deferred rescale (THR=8), interior-tile mask skip
      const bool noMask = (kt * 64 + 63) <= (qm0 + wid * 16);   // wave-uniform
      float p[4][4], rmax4[4];
#pragma unroll
      for (int j = 0; j < 4; ++j){
        const int qi = qm0 + wid * 16 + lhi * 4 + j;
        float rmax = -3e38f;
#pragma unroll
        for (int n = 0; n < 4; ++n){
          float sv = s[n][j] * scale2;
          if (!noMask){ int ki = kt * 64 + n * 16 + l15; if (ki > qi) sv = -3e38f; }
          p[n][j] = sv;
          rmax = fmaxf(rmax, sv);
        }
        rmax = fmaxf(rmax, __shfl_xor(rmax, 1));
        rmax = fmaxf(rmax, __shfl_xor(rmax, 2));
        rmax = fmaxf(rmax, __shfl_xor(rmax, 4));
        rmax = fmaxf(rmax, __shfl_xor(rmax, 8));
        rmax4[j] = rmax;
      }
      bool need = (rmax4[0] > mrow[0] + 8.f) | (rmax4[1] > mrow[1] + 8.f) |
                  (rmax4[2] > mrow[2] + 8.f) | (rmax4[3] > mrow[3] + 8.f);
      if (__any(need)){
#pragma unroll
        for (int j = 0; j < 4; ++j){
          float mnew = fmaxf(mrow[j], rmax4[j]);
          float osc = exp2f(mrow[j] - mnew);
          lrow[j] *= osc;
          mrow[j] = mnew;
#pragma unroll
          for (int f = 0; f < 8; ++f) acc_o[f][j] *= osc;
        }
      }
#pragma unroll
      for (int j = 0; j < 4; ++j){
        float rsum = 0.f;
#pragma unroll
        for (int n = 0; n < 4; ++n){
          float pv = exp2f(p[n][j] - mrow[j]);
          p[n][j] = pv;
          rsum += pv;
        }
        rsum += __shfl_xor(rsum, 1);
        rsum += __shfl_xor(rsum, 2);
        rsum += __shfl_xor(rsum, 4);
        rsum += __shfl_xor(rsum, 8);
        lrow[j] += rsum;
      }

      // P -> per-wave LDS, element-swizzled
#pragma unroll
      for (int j = 0; j < 4; ++j){
        const int prow = lhi * 4 + j;
#pragma unroll
        for (int n = 0; n < 4; ++n)
          Pw[prow * 64 + ((n * 16 + l15) ^ ((prow & 7) << 3))] = f2bf(p[n][j]);
      }

      // O += P @ V
#pragma unroll
      for (int kc2 = 0; kc2 < 2; ++kc2){
        bs8 pf = *(const bs8*)(Pw + l15 * 64 + (((kc2 * 4 + lhi) ^ sw) << 3));
#pragma unroll
        for (int f = 0; f < 8; ++f){
          bs8 vf = *(const bs8*)(Vs + (f * 16 + l15) * 64 + (((kc2 * 4 + lhi) ^ sw) << 3));
          acc_o[f] = __builtin_amdgcn_mfma_f32_16x16x32_bf16(pf, vf, acc_o[f], 0, 0, 0);
        }
      }
    }
    __syncthreads();
  }

#pragma unroll
  for (int f = 0; f < 8; ++f)
#pragma unroll
    for (int j = 0; j < 4; ++j){
      int t = qm0 + wid * 16 + lhi * 4 + j;
      float ov = acc_o[f][j] / lrow[j];
      O[((size_t)b * 2048 + t) * 2048 + h * 128 + f * 16 + l15] = f2bf(ov);
    }
}

extern "C" void kernel_launch(void* const* d_in, const int* in_sizes, int n_in,
                              void* d_out, int out_size, void* d_ws, size_t ws_size,
                              hipStream_t stream){
  constexpr int Bc = 2, Tc = 2048, Cc = 2048, Hc = 16, HDc = 128, RDc = 64, KVRc = 512, QRc = 1024;
  constexpr int Mx = Bc * Tc; // 4096
  const float* x     = (const float*)d_in[0];
  const float* w_dq  = (const float*)d_in[1];
  const float* w_uq  = (const float*)d_in[2];
  const float* w_dkv = (const float*)d_in[3];
  const float* w_uk  = (const float*)d_in[4];
  const float* w_uv  = (const float*)d_in[5];
  const float* w_qr  = (const float*)d_in[6];
  const float* w_kr  = (const float*)d_in[7];
  const float* w_o   = (const float*)d_in[8];
  const float* fc    = (const float*)d_in[9];
  const float* fs    = (const float*)d_in[10];
  float* out = (float*)d_out;

  char* ws = (char*)d_ws;
  size_t off = 0;
  auto alloc = [&](size_t elems) -> ushort_t* {
    ushort_t* p = (ushort_t*)(ws + off);
    off += ((elems * 2) + 255) & ~(size_t)255;
    return p;
  };
  ushort_t* xb    = alloc((size_t)Mx * Cc);
  // BT1 group (adjacent, N-order): [cq 1024 | ckv 512 | kr 1024], K=2048
  ushort_t* wdqT  = alloc((size_t)QRc * Cc);
  ushort_t* wdkvT = alloc((size_t)KVRc * Cc);
  ushort_t* wkrT  = alloc((size_t)(Hc * RDc) * Cc);
  // BT2 group: [qc 2048 | qr 1024], K=1024
  ushort_t* wuqT  = alloc((size_t)(Hc * HDc) * QRc);
  ushort_t* wqrT  = alloc((size_t)(Hc * RDc) * QRc);
  // BT3 group: [kc 2048 | v 2048], K=512
  ushort_t* wukT  = alloc((size_t)(Hc * HDc) * KVRc);
  ushort_t* wuvT  = alloc((size_t)(Hc * HDc) * KVRc);
  ushort_t* woT   = alloc((size_t)Cc * (Hc * HDc));
  ushort_t* comb1 = alloc((size_t)Mx * 2560);   // [cq | ckv | kr]
  ushort_t* qcomb = alloc((size_t)Mx * 3072);   // [qc | qr]
  ushort_t* kvcomb= alloc((size_t)Mx * 4096);   // [kc | v]
  ushort_t* Qa    = alloc((size_t)Bc * Hc * Tc * 192);
  ushort_t* Ka    = alloc((size_t)Bc * Hc * Tc * 192);
  ushort_t* vT    = alloc((size_t)Bc * Hc * HDc * Tc);
  ushort_t* O     = xb;  // alias: xb dead after GEMM1

  cast_x<<<dim3(((size_t)Mx * Cc) / 1024), 256, 0, stream>>>(x, xb);

  transpose_cast<<<dim3(QRc / 32, Cc / 32), dim3(32, 8), 0, stream>>>(w_dq, wdqT, Cc, QRc);
  transpose_cast<<<dim3(KVRc / 32, Cc / 32), dim3(32, 8), 0, stream>>>(w_dkv, wdkvT, Cc, KVRc);
  transpose_cast<<<dim3((Hc * RDc) / 32, Cc / 32), dim3(32, 8), 0, stream>>>(w_kr, wkrT, Cc, Hc * RDc);
  transpose_cast<<<dim3((Hc * HDc) / 32, QRc / 32), dim3(32, 8), 0, stream>>>(w_uq, wuqT, QRc, Hc * HDc);
  transpose_cast<<<dim3((Hc * RDc) / 32, QRc / 32), dim3(32, 8), 0, stream>>>(w_qr, wqrT, QRc, Hc * RDc);
  transpose_cast<<<dim3((Hc * HDc) / 32, KVRc / 32), dim3(32, 8), 0, stream>>>(w_uk, wukT, KVRc, Hc * HDc);
  transpose_cast<<<dim3((Hc * HDc) / 32, KVRc / 32), dim3(32, 8), 0, stream>>>(w_uv, wuvT, KVRc, Hc * HDc);
  transpose_cast<<<dim3(Cc / 32, (Hc * HDc) / 32), dim3(32, 8), 0, stream>>>(w_o, woT, Hc * HDc, Cc);

  // GEMM1: x @ [w_dq | w_dkv | w_kr]  -> comb1 [4096][2560]
  gemm256<ushort_t><<<dim3((Mx / 256) * (2560 / 256)), 512, 0, stream>>>(xb, Cc, wdqT, comb1, Mx, 2560, Cc);
  // GEMM2: cq @ [w_uq | w_qr] -> qcomb [4096][3072]
  gemm256<ushort_t><<<dim3((Mx / 256) * (3072 / 256)), 512, 0, stream>>>(comb1, 2560, wuqT, qcomb, Mx, 3072, QRc);
  // GEMM3: ckv @ [w_uk | w_uv] -> kvcomb [4096][4096]
  gemm256<ushort_t><<<dim3((Mx / 256) * (4096 / 256)), 512, 0, stream>>>(comb1 + QRc, 2560, wukT, kvcomb, Mx, 4096, KVRc);

  assemble_qk<<<Mx, 256, 0, stream>>>(qcomb, 3072, qcomb + 2048, 3072, fc, fs, Qa);
  assemble_qk<<<Mx, 256, 0, stream>>>(kvcomb, 4096, comb1 + 1536, 2560, fc, fs, Ka);
  transpose_v<<<dim3(Tc / 32, HDc / 32, Bc * Hc), dim3(32, 8), 0, stream>>>(kvcomb + 2048, 4096, vT);

  attn_kernel<<<dim3(Bc * Hc, 16), 512, 0, stream>>>(Qa, Ka, vT, O);

  // GEMM4: O @ w_o -> out [4096][2048] fp32
  gemm256<float><<<dim3((Mx / 256) * (Cc / 256)), 512, 0, stream>>>(O, Hc * HDc, woT, out, Mx, Cc, Hc * HDc);
}

// Round 4
// 367.613 us; speedup vs baseline: 1.6966x; 1.1147x over previous
//
#include <hip/hip_runtime.h>

typedef unsigned short ushort_t;
typedef __attribute__((ext_vector_type(8))) short bs8;       // 8 x bf16 (4 VGPR)
typedef __attribute__((ext_vector_type(4))) float f32x4;
typedef __attribute__((ext_vector_type(4))) unsigned short u16x4;

#define DEV __device__ __forceinline__

DEV unsigned short f2bf(float f){
  unsigned u = __float_as_uint(f);
  u += 0x7fffu + ((u >> 16) & 1u);           // round-to-nearest-even
  return (unsigned short)(u >> 16);
}
DEV float bf2f(unsigned short h){ return __uint_as_float(((unsigned)h) << 16); }

DEV void gl2lds16(const void* g, void* l){
  __builtin_amdgcn_global_load_lds((const __attribute__((address_space(1))) void*)g,
                                   (__attribute__((address_space(3))) void*)l, 16, 0, 0);
}

DEV void st_out(ushort_t* C, size_t i, float v){ C[i] = f2bf(v); }
DEV void st_out(float*    C, size_t i, float v){ C[i] = v; }

// ---------------- cast x (fp32 -> bf16), 4 elems/thread ----------------
__global__ __launch_bounds__(256) void cast_x(const float* __restrict__ in,
                                              ushort_t* __restrict__ outb){
  size_t i = ((size_t)blockIdx.x * 256 + threadIdx.x) * 4;
  float4 v = *(const float4*)(in + i);
  u16x4 o;
  o[0] = f2bf(v.x); o[1] = f2bf(v.y); o[2] = f2bf(v.z); o[3] = f2bf(v.w);
  *(u16x4*)(outb + i) = o;
}

// ---------------- transpose-cast weight: in[K][N] fp32 -> out[N][K] bf16 ----------------
__global__ __launch_bounds__(256) void transpose_cast(const float* __restrict__ in,
                                                      ushort_t* __restrict__ out,
                                                      int K, int N){
  __shared__ float tile[32][33];
  int k0 = blockIdx.y * 32, n0 = blockIdx.x * 32;
  int tx = threadIdx.x, ty = threadIdx.y;
  for (int r = ty; r < 32; r += 8)
    tile[r][tx] = in[(size_t)(k0 + r) * N + n0 + tx];
  __syncthreads();
  for (int r = ty; r < 32; r += 8)
    out[(size_t)(n0 + r) * K + k0 + tx] = f2bf(tile[tx][r]);
}

// ---------------- bf16 transpose per (b,h): v[M][ldv] -> vT[BH][128][T] ----------------
__global__ __launch_bounds__(256) void transpose_v(const ushort_t* __restrict__ v, int ldv,
                                                   ushort_t* __restrict__ vT){
  __shared__ ushort_t tile[32][33];
  int bh = blockIdx.z; int b = bh >> 4, h = bh & 15;
  int t0 = blockIdx.x * 32, d0 = blockIdx.y * 32;
  int tx = threadIdx.x, ty = threadIdx.y;
  for (int r = ty; r < 32; r += 8)
    tile[r][tx] = v[((size_t)(b * 2048 + t0 + r)) * ldv + h * 128 + d0 + tx];
  __syncthreads();
  for (int r = ty; r < 32; r += 8)
    vT[((size_t)bh * 128 + d0 + r) * 2048 + t0 + tx] = tile[tx][r];
}

// ---------------- assemble Q or K: concat core[M][.] + rope(rot[M][.]) -> [BH][T][192] ----------------
__global__ __launch_bounds__(256) void assemble_qk(const ushort_t* __restrict__ core, int cs,
                                                   const ushort_t* __restrict__ rot, int rs,
                                                   const float* __restrict__ fc,
                                                   const float* __restrict__ fs,
                                                   ushort_t* __restrict__ outb){
  const int m = blockIdx.x;
  const int b = m >> 11, t = m & 2047;
  for (int i = threadIdx.x; i < 2048; i += 256){
    int h = i >> 7, d = i & 127;
    outb[((size_t)(b * 16 + h) * 2048 + t) * 192 + d] = core[(size_t)m * cs + i];
  }
  for (int p = threadIdx.x; p < 512; p += 256){
    int h = p >> 5, i = p & 31;
    float tr = bf2f(rot[(size_t)m * rs + h * 64 + 2 * i]);
    float ti = bf2f(rot[(size_t)m * rs + h * 64 + 2 * i + 1]);
    float c = fc[t * 32 + i], s = fs[t * 32 + i];
    size_t base = ((size_t)(b * 16 + h) * 2048 + t) * 192 + 128;
    outb[base + 2 * i]     = f2bf(tr * c - ti * s);
    outb[base + 2 * i + 1] = f2bf(tr * s + ti * c);
  }
}

// ================= 256x256 8-phase GEMM (T2+T3+T4+T5), BK=64 =================
template<typename OT>
__global__ __launch_bounds__(512, 2) void gemm256(const ushort_t* __restrict__ A, int lda,
                                                  const ushort_t* __restrict__ BT,
                                                  OT* __restrict__ C,
                                                  int M, int N, int K){
  __shared__ __align__(16) ushort_t lds[65536];   // 128 KiB
  const int tid = threadIdx.x, lane = tid & 63, wid = tid >> 6;
  const int l15 = lane & 15, lhi = lane >> 4;
  const int wr = wid >> 2, wc = wid & 3;

  const int nbx = M >> 8;
  const int nwg = gridDim.x;
  const int orig = blockIdx.x;
  const int wg = (orig & 7) * (nwg >> 3) + (orig >> 3);
  const int m0 = (wg % nbx) << 8;
  const int n0 = (wg / nbx) << 8;

  const int trow = tid >> 3;
  const int tcsrc = (tid & 7) ^ (trow & 7);
  const ushort_t* gA[2][2];
  const ushort_t* gB[2][2];
#pragma unroll
  for (int h = 0; h < 2; ++h)
#pragma unroll
    for (int i = 0; i < 2; ++i){
      gA[h][i] = A  + (size_t)(m0 + h * 128 + i * 64 + trow) * lda + tcsrc * 8;
      gB[h][i] = BT + (size_t)(n0 + h * 128 + i * 64 + trow) * K   + tcsrc * 8;
    }

  auto STAGE_A = [&](int buf, int h, int kt){
    gl2lds16(gA[h][0] + (size_t)kt * 64, lds + buf * 32768 + h * 8192 + tid * 8);
    gl2lds16(gA[h][1] + (size_t)kt * 64, lds + buf * 32768 + h * 8192 + 4096 + tid * 8);
  };
  auto STAGE_B = [&](int buf, int h, int kt){
    gl2lds16(gB[h][0] + (size_t)kt * 64, lds + buf * 32768 + 16384 + h * 8192 + tid * 8);
    gl2lds16(gB[h][1] + (size_t)kt * 64, lds + buf * 32768 + 16384 + h * 8192 + 4096 + tid * 8);
  };

  const int ck0 = ((lhi) ^ (l15 & 7)) << 3;
  const int ck1 = ((4 + lhi) ^ (l15 & 7)) << 3;

  f32x4 acc[8][4] = {};
  bs8 aF[4][2], bLo[2][2], bHi[2][2];

  auto RDA = [&](int buf, int mq){
#pragma unroll
    for (int m = 0; m < 4; ++m){
      const ushort_t* r = lds + buf * 32768 + wr * 8192 + ((mq + m) * 16 + l15) * 64;
      aF[m][0] = *(const bs8*)(r + ck0);
      aF[m][1] = *(const bs8*)(r + ck1);
    }
  };
  auto RDB = [&](int buf, int nq, bs8 (&br)[2][2]){
#pragma unroll
    for (int n = 0; n < 2; ++n){
      const ushort_t* r = lds + buf * 32768 + 16384 + (wc >> 1) * 8192 +
                          ((wc & 1) * 64 + (nq + n) * 16 + l15) * 64;
      br[n][0] = *(const bs8*)(r + ck0);
      br[n][1] = *(const bs8*)(r + ck1);
    }
  };
  auto MMA = [&](int mq, int nq, bs8 (&br)[2][2]){
    __builtin_amdgcn_s_setprio(1);
#pragma unroll
    for (int m = 0; m < 4; ++m)
#pragma unroll
      for (int n = 0; n < 2; ++n){
        acc[mq + m][nq + n] = __builtin_amdgcn_mfma_f32_16x16x32_bf16(aF[m][0], br[n][0], acc[mq + m][nq + n], 0, 0, 0);
        acc[mq + m][nq + n] = __builtin_amdgcn_mfma_f32_16x16x32_bf16(aF[m][1], br[n][1], acc[mq + m][nq + n], 0, 0, 0);
      }
    __builtin_amdgcn_s_setprio(0);
  };

#define BAR() __builtin_amdgcn_s_barrier()
#define LGK() asm volatile("s_waitcnt lgkmcnt(0)" ::: "memory")
#define VMC4() asm volatile("s_waitcnt vmcnt(4)" ::: "memory")

  const int nkt = K >> 6;
  const int nIter = K >> 7;

  STAGE_A(0, 0, 0); STAGE_A(0, 1, 0); STAGE_B(0, 0, 0); STAGE_B(0, 1, 0);
  STAGE_B(1, 0, 1); STAGE_B(1, 1, 1);
  VMC4();
  BAR();

  for (int it = 0; it < nIter; ++it){
    const int kt1 = 2 * it + 1;
    int kt2 = 2 * it + 2; if (kt2 > nkt - 1) kt2 = nkt - 1;
    int kt3 = 2 * it + 3; if (kt3 > nkt - 1) kt3 = nkt - 1;
    RDA(0, 0); RDB(0, 0, bLo);
    STAGE_A(1, 0, kt1);
    BAR(); LGK(); MMA(0, 0, bLo); BAR();
    RDB(0, 2, bHi);
    STAGE_A(1, 1, kt1);
    BAR(); LGK(); MMA(0, 2, bHi); BAR();
    RDA(0, 4);
    STAGE_B(0, 0, kt2);
    BAR(); LGK(); MMA(4, 0, bLo); BAR();
    STAGE_B(0, 1, kt2);
    BAR(); LGK(); MMA(4, 2, bHi);
    VMC4(); BAR();
    RDA(1, 0); RDB(1, 0, bLo);
    STAGE_A(0, 0, kt2);
    BAR(); LGK(); MMA(0, 0, bLo); BAR();
    RDB(1, 2, bHi);
    STAGE_A(0, 1, kt2);
    BAR(); LGK(); MMA(0, 2, bHi); BAR();
    RDA(1, 4);
    STAGE_B(1, 0, kt3);
    BAR(); LGK(); MMA(4, 0, bLo); BAR();
    STAGE_B(1, 1, kt3);
    BAR(); LGK(); MMA(4, 2, bHi);
    VMC4(); BAR();
  }
#undef BAR
#undef LGK
#undef VMC4

#pragma unroll
  for (int m = 0; m < 8; ++m){
    const int r = m0 + wr * 128 + m * 16 + lhi * 4;
#pragma unroll
    for (int n = 0; n < 4; ++n){
      const int c = n0 + wc * 64 + n * 16 + l15;
#pragma unroll
      for (int j = 0; j < 4; ++j)
        st_out(C, (size_t)(r + j) * N + c, acc[m][n][j]);
    }
  }
}

// ============ flash attention v3: swapped QK^T, in-register softmax/P ============
// 4 waves x 32 q-rows (QB=128). S^T = mfma(K,Q) with permuted kv->A-row mapping so
// each lane's P values are exactly the PV B-fragment (zero-op relayout).
__global__ __launch_bounds__(256, 2) void attn_kernel(const ushort_t* __restrict__ Qa,
                                                      const ushort_t* __restrict__ Ka,
                                                      const ushort_t* __restrict__ VT,
                                                      ushort_t* __restrict__ O){
  __shared__ __align__(16) ushort_t Ks[64 * 192];    // 24 KB, hK-swizzled
  __shared__ __align__(16) ushort_t Vs[128 * 64];    // 16 KB, row&7-swizzled
  const int tid = threadIdx.x, lane = tid & 63, wid = tid >> 6;
  const int bh = blockIdx.x;
  const int yy = blockIdx.y;
  const int qb = (yy < 8) ? (15 - yy) : (yy - 8);    // pair heavy+light per CU
  const int b = bh >> 4, h = bh & 15;
  const int qm0 = qb * 128;
  const int l15 = lane & 15, lhi = lane >> 4;
  const float scale2 = 0.07216878364870323f * 1.4426950408889634f; // 1/sqrt(192)*log2e

  // Q registers: 2 q-groups of 16 rows, 6 k-chunks (B-fragment layout)
  bs8 qf[2][6];
#pragma unroll
  for (int qg = 0; qg < 2; ++qg){
    const size_t qrow = ((size_t)bh * 2048 + qm0 + wid * 32 + qg * 16 + l15) * 192;
#pragma unroll
    for (int kc = 0; kc < 6; ++kc)
      qf[qg][kc] = *(const bs8*)(Qa + qrow + kc * 32 + lhi * 8);
  }

  f32x4 acc[2][8] = {};                              // O^T: lane q=l15(qg), d=f*16+lhi*4+j
  float mrow[2] = {-1e30f, -1e30f};
  float lrow[2] = {0.f, 0.f};

  const ushort_t* Kbh = Ka + (size_t)bh * 2048 * 192;
  const ushort_t* Vbh = VT + (size_t)bh * 128 * 2048;

  // staging sources (inverse-swizzled global addresses, rule #21)
  const ushort_t* ksrc[6];
#pragma unroll
  for (int i = 0; i < 6; ++i){
    int c = i * 256 + tid;
    int row = c / 24, col = c % 24;
    int hk = (row & 3) | (((row >> 3) & 1) << 2);
    ksrc[i] = Kbh + (size_t)row * 192 + (col ^ hk) * 8;
  }
  const ushort_t* vsrc[4];
#pragma unroll
  for (int i = 0; i < 4; ++i){
    int c = i * 256 + tid;
    int d = c >> 3, col = c & 7;
    vsrc[i] = Vbh + (size_t)d * 2048 + (col ^ (d & 7)) * 8;
  }

  const int nkt = 2 * qb + 2;
  const int mylast = (qm0 + wid * 32 + 31) >> 6;
  const int hkr = (l15 & 3) | (((l15 >> 2) & 1) << 2);  // read-side K hash (indep. of m)

  for (int kt = 0; kt < nkt; ++kt){
#pragma unroll
    for (int i = 0; i < 6; ++i) gl2lds16(ksrc[i] + (size_t)kt * 12288, Ks + (i * 256 + tid) * 8);
#pragma unroll
    for (int i = 0; i < 4; ++i) gl2lds16(vsrc[i] + kt * 64, Vs + (i * 256 + tid) * 8);
    __syncthreads();

    if (kt <= mylast){
      // S^T = K x Q^T: per MFMA m, A-row r holds physical kv pi(m,r)
      f32x4 s[2][4] = {};
#pragma unroll
      for (int kc = 0; kc < 6; ++kc){
        bs8 kf4[4];
#pragma unroll
        for (int m = 0; m < 4; ++m){
          int row = ((m >> 1) << 5) + ((l15 >> 2) << 3) + ((m & 1) << 2) + (l15 & 3);
          kf4[m] = *(const bs8*)(Ks + row * 192 + (((kc * 4 + lhi) ^ hkr) << 3));
        }
#pragma unroll
        for (int qg = 0; qg < 2; ++qg)
#pragma unroll
          for (int m = 0; m < 4; ++m)
            s[qg][m] = __builtin_amdgcn_mfma_f32_16x16x32_bf16(kf4[m], qf[qg][kc], s[qg][m], 0, 0, 0);
      }

      // per-lane online softmax: lane holds 16 kv values for ONE q per group
      const bool noMask = (kt * 64 + 63) <= (qm0 + wid * 32);   // wave-uniform
#pragma unroll
      for (int qg = 0; qg < 2; ++qg){
        const int qi = qm0 + wid * 32 + qg * 16 + l15;
        float rmax = -3e38f;
#pragma unroll
        for (int m = 0; m < 4; ++m)
#pragma unroll
          for (int j = 0; j < 4; ++j){
            float sv = s[qg][m][j] * scale2;
            if (!noMask){
              int ki = kt * 64 + ((m >> 1) << 5) + (lhi << 3) + ((m & 1) << 2) + j;
              if (ki > qi) sv = -3e38f;
            }
            s[qg][m][j] = sv;
            rmax = fmaxf(rmax, sv);
          }
        rmax = fmaxf(rmax, __shfl_xor(rmax, 16));
        rmax = fmaxf(rmax, __shfl_xor(rmax, 32));
        float mnew = fmaxf(mrow[qg], rmax);
        float osc = exp2f(mrow[qg] - mnew);
        float rsum = 0.f;
#pragma unroll
        for (int m = 0; m < 4; ++m)
#pragma unroll
          for (int j = 0; j < 4; ++j){
            float pv = exp2f(s[qg][m][j] - mnew);
            s[qg][m][j] = pv;
            rsum += pv;
          }
        rsum += __shfl_xor(rsum, 16);
        rsum += __shfl_xor(rsum, 32);
        lrow[qg] = lrow[qg] * osc + rsum;
        mrow[qg] = mnew;
#pragma unroll
        for (int f = 0; f < 8; ++f) acc[qg][f] *= osc;
      }

      // pack P in-register: pb[qg][kc2] holds P[q=l15][kv=kc2*32+lhi*8+0..7]
      bs8 pb[2][2];
#pragma unroll
      for (int qg = 0; qg < 2; ++qg)
#pragma unroll
        for (int kc2 = 0; kc2 < 2; ++kc2)
#pragma unroll
          for (int t = 0; t < 8; ++t)
            pb[qg][kc2][t] = (short)f2bf(s[qg][2 * kc2 + (t >> 2)][t & 3]);

      // O^T += V^T x P^T
#pragma unroll
      for (int kc2 = 0; kc2 < 2; ++kc2)
#pragma unroll
        for (int f = 0; f < 8; ++f){
          bs8 vf = *(const bs8*)(Vs + (f * 16 + l15) * 64 + (((kc2 * 4 + lhi) ^ (l15 & 7)) << 3));
#pragma unroll
          for (int qg = 0; qg < 2; ++qg)
            acc[qg][f] = __builtin_amdgcn_mfma_f32_16x16x32_bf16(vf, pb[qg][kc2], acc[qg][f], 0, 0, 0);
        }
    }
    __syncthreads();
  }

  // epilogue: O[t][h*128+d], lane writes 4 contiguous d per (qg,f)
#pragma unroll
  for (int qg = 0; qg < 2; ++qg){
    float rl = 1.0f / lrow[qg];
    int t = qm0 + wid * 32 + qg * 16 + l15;
#pragma unroll
    for (int f = 0; f < 8; ++f){
      u16x4 o;
#pragma unroll
      for (int j = 0; j < 4; ++j) o[j] = f2bf(acc[qg][f][j] * rl);
      *(u16x4*)(O + ((size_t)b * 2048 + t) * 2048 + h * 128 + f * 16 + lhi * 4) = o;
    }
  }
}

extern "C" void kernel_launch(void* const* d_in, const int* in_sizes, int n_in,
                              void* d_out, int out_size, void* d_ws, size_t ws_size,
                              hipStream_t stream){
  constexpr int Bc = 2, Tc = 2048, Cc = 2048, Hc = 16, HDc = 128, RDc = 64, KVRc = 512, QRc = 1024;
  constexpr int Mx = Bc * Tc; // 4096
  const float* x     = (const float*)d_in[0];
  const float* w_dq  = (const float*)d_in[1];
  const float* w_uq  = (const float*)d_in[2];
  const float* w_dkv = (const float*)d_in[3];
  const float* w_uk  = (const float*)d_in[4];
  const float* w_uv  = (const float*)d_in[5];
  const float* w_qr  = (const float*)d_in[6];
  const float* w_kr  = (const float*)d_in[7];
  const float* w_o   = (const float*)d_in[8];
  const float* fc    = (const float*)d_in[9];
  const float* fs    = (const float*)d_in[10];
  float* out = (float*)d_out;

  char* ws = (char*)d_ws;
  size_t off = 0;
  auto alloc = [&](size_t elems) -> ushort_t* {
    ushort_t* p = (ushort_t*)(ws + off);
    off += ((elems * 2) + 255) & ~(size_t)255;
    return p;
  };
  ushort_t* xb    = alloc((size_t)Mx * Cc);
  ushort_t* wdqT  = alloc((size_t)QRc * Cc);
  ushort_t* wdkvT = alloc((size_t)KVRc * Cc);
  ushort_t* wkrT  = alloc((size_t)(Hc * RDc) * Cc);
  ushort_t* wuqT  = alloc((size_t)(Hc * HDc) * QRc);
  ushort_t* wqrT  = alloc((size_t)(Hc * RDc) * QRc);
  ushort_t* wukT  = alloc((size_t)(Hc * HDc) * KVRc);
  ushort_t* wuvT  = alloc((size_t)(Hc * HDc) * KVRc);
  ushort_t* woT   = alloc((size_t)Cc * (Hc * HDc));
  ushort_t* comb1 = alloc((size_t)Mx * 2560);   // [cq | ckv | kr]
  ushort_t* qcomb = alloc((size_t)Mx * 3072);   // [qc | qr]
  ushort_t* kvcomb= alloc((size_t)Mx * 4096);   // [kc | v]
  ushort_t* Qa    = alloc((size_t)Bc * Hc * Tc * 192);
  ushort_t* Ka    = alloc((size_t)Bc * Hc * Tc * 192);
  ushort_t* vT    = alloc((size_t)Bc * Hc * HDc * Tc);
  ushort_t* O     = xb;  // alias: xb dead after GEMM1

  cast_x<<<dim3(((size_t)Mx * Cc) / 1024), 256, 0, stream>>>(x, xb);

  transpose_cast<<<dim3(QRc / 32, Cc / 32), dim3(32, 8), 0, stream>>>(w_dq, wdqT, Cc, QRc);
  transpose_cast<<<dim3(KVRc / 32, Cc / 32), dim3(32, 8), 0, stream>>>(w_dkv, wdkvT, Cc, KVRc);
  transpose_cast<<<dim3((Hc * RDc) / 32, Cc / 32), dim3(32, 8), 0, stream>>>(w_kr, wkrT, Cc, Hc * RDc);
  transpose_cast<<<dim3((Hc * HDc) / 32, QRc / 32), dim3(32, 8), 0, stream>>>(w_uq, wuqT, QRc, Hc * HDc);
  transpose_cast<<<dim3((Hc * RDc) / 32, QRc / 32), dim3(32, 8), 0, stream>>>(w_qr, wqrT, QRc, Hc * RDc);
  transpose_cast<<<dim3((Hc * HDc) / 32, KVRc / 32), dim3(32, 8), 0, stream>>>(w_uk, wukT, KVRc, Hc * HDc);
  transpose_cast<<<dim3((Hc * HDc) / 32, KVRc / 32), dim3(32, 8), 0, stream>>>(w_uv, wuvT, KVRc, Hc * HDc);
  transpose_cast<<<dim3(Cc / 32, (Hc * HDc) / 32), dim3(32, 8), 0, stream>>>(w_o, woT, Hc * HDc, Cc);

  gemm256<ushort_t><<<dim3((Mx / 256) * (2560 / 256)), 512, 0, stream>>>(xb, Cc, wdqT, comb1, Mx, 2560, Cc);
  gemm256<ushort_t><<<dim3((Mx / 256) * (3072 / 256)), 512, 0, stream>>>(comb1, 2560, wuqT, qcomb, Mx, 3072, QRc);
  gemm256<ushort_t><<<dim3((Mx / 256) * (4096 / 256)), 512, 0, stream>>>(comb1 + QRc, 2560, wukT, kvcomb, Mx, 4096, KVRc);

  assemble_qk<<<Mx, 256, 0, stream>>>(qcomb, 3072, qcomb + 2048, 3072, fc, fs, Qa);
  assemble_qk<<<Mx, 256, 0, stream>>>(kvcomb, 4096, comb1 + 1536, 2560, fc, fs, Ka);
  transpose_v<<<dim3(Tc / 32, HDc / 32, Bc * Hc), dim3(32, 8), 0, stream>>>(kvcomb + 2048, 4096, vT);

  attn_kernel<<<dim3(Bc * Hc, 16), 256, 0, stream>>>(Qa, Ka, vT, O);

  gemm256<float><<<dim3((Mx / 256) * (Cc / 256)), 512, 0, stream>>>(O, Hc * HDc, woT, out, Mx, Cc, Hc * HDc);
}

// Round 5
// 344.922 us; speedup vs baseline: 1.8082x; 1.0658x over previous
//
#include <hip/hip_runtime.h>

typedef unsigned short ushort_t;
typedef __attribute__((ext_vector_type(8))) short bs8;       // 8 x bf16 (4 VGPR)
typedef __attribute__((ext_vector_type(4))) float f32x4;
typedef __attribute__((ext_vector_type(4))) unsigned short u16x4;

#define DEV __device__ __forceinline__

DEV unsigned short f2bf(float f){
  unsigned u = __float_as_uint(f);
  u += 0x7fffu + ((u >> 16) & 1u);           // round-to-nearest-even
  return (unsigned short)(u >> 16);
}
DEV float bf2f(unsigned short h){ return __uint_as_float(((unsigned)h) << 16); }

DEV unsigned cvt_pk_bf16(float lo, float hi){
  unsigned r;
  asm volatile("v_cvt_pk_bf16_f32 %0, %1, %2" : "=v"(r) : "v"(lo), "v"(hi));
  return r;
}

DEV void gl2lds16(const void* g, void* l){
  __builtin_amdgcn_global_load_lds((const __attribute__((address_space(1))) void*)g,
                                   (__attribute__((address_space(3))) void*)l, 16, 0, 0);
}

DEV void st_out(ushort_t* C, size_t i, float v){ C[i] = f2bf(v); }
DEV void st_out(float*    C, size_t i, float v){ C[i] = v; }

// ---------------- cast x (fp32 -> bf16), 4 elems/thread ----------------
__global__ __launch_bounds__(256) void cast_x(const float* __restrict__ in,
                                              ushort_t* __restrict__ outb){
  size_t i = ((size_t)blockIdx.x * 256 + threadIdx.x) * 4;
  float4 v = *(const float4*)(in + i);
  u16x4 o;
  o[0] = f2bf(v.x); o[1] = f2bf(v.y); o[2] = f2bf(v.z); o[3] = f2bf(v.w);
  *(u16x4*)(outb + i) = o;
}

// ---------------- transpose-cast weight: in[K][N] fp32 -> out[N][K] bf16 ----------------
__global__ __launch_bounds__(256) void transpose_cast(const float* __restrict__ in,
                                                      ushort_t* __restrict__ out,
                                                      int K, int N){
  __shared__ float tile[32][33];
  int k0 = blockIdx.y * 32, n0 = blockIdx.x * 32;
  int tx = threadIdx.x, ty = threadIdx.y;
  for (int r = ty; r < 32; r += 8)
    tile[r][tx] = in[(size_t)(k0 + r) * N + n0 + tx];
  __syncthreads();
  for (int r = ty; r < 32; r += 8)
    out[(size_t)(n0 + r) * K + k0 + tx] = f2bf(tile[tx][r]);
}

// ---------------- bf16 transpose per (b,h): v[M][ldv] -> vT[BH][128][T] ----------------
__global__ __launch_bounds__(256) void transpose_v(const ushort_t* __restrict__ v, int ldv,
                                                   ushort_t* __restrict__ vT){
  __shared__ ushort_t tile[32][33];
  int bh = blockIdx.z; int b = bh >> 4, h = bh & 15;
  int t0 = blockIdx.x * 32, d0 = blockIdx.y * 32;
  int tx = threadIdx.x, ty = threadIdx.y;
  for (int r = ty; r < 32; r += 8)
    tile[r][tx] = v[((size_t)(b * 2048 + t0 + r)) * ldv + h * 128 + d0 + tx];
  __syncthreads();
  for (int r = ty; r < 32; r += 8)
    vT[((size_t)bh * 128 + d0 + r) * 2048 + t0 + tx] = tile[tx][r];
}

// ---------------- assemble Q or K: concat core + rope(rot), optional pre-scale ----------------
__global__ __launch_bounds__(256) void assemble_qk(const ushort_t* __restrict__ core, int cs,
                                                   const ushort_t* __restrict__ rot, int rs,
                                                   const float* __restrict__ fc,
                                                   const float* __restrict__ fs,
                                                   ushort_t* __restrict__ outb, float scale){
  const int m = blockIdx.x;
  const int b = m >> 11, t = m & 2047;
  for (int i = threadIdx.x; i < 2048; i += 256){
    int h = i >> 7, d = i & 127;
    outb[((size_t)(b * 16 + h) * 2048 + t) * 192 + d] = f2bf(bf2f(core[(size_t)m * cs + i]) * scale);
  }
  for (int p = threadIdx.x; p < 512; p += 256){
    int h = p >> 5, i = p & 31;
    float tr = bf2f(rot[(size_t)m * rs + h * 64 + 2 * i]);
    float ti = bf2f(rot[(size_t)m * rs + h * 64 + 2 * i + 1]);
    float c = fc[t * 32 + i], s = fs[t * 32 + i];
    size_t base = ((size_t)(b * 16 + h) * 2048 + t) * 192 + 128;
    outb[base + 2 * i]     = f2bf((tr * c - ti * s) * scale);
    outb[base + 2 * i + 1] = f2bf((tr * s + ti * c) * scale);
  }
}

// ================= 256x256 8-phase GEMM (T2+T3+T4+T5), BK=64 =================
template<typename OT>
__global__ __launch_bounds__(512, 2) void gemm256(const ushort_t* __restrict__ A, int lda,
                                                  const ushort_t* __restrict__ BT,
                                                  OT* __restrict__ C,
                                                  int M, int N, int K){
  __shared__ __align__(16) ushort_t lds[65536];   // 128 KiB
  const int tid = threadIdx.x, lane = tid & 63, wid = tid >> 6;
  const int l15 = lane & 15, lhi = lane >> 4;
  const int wr = wid >> 2, wc = wid & 3;

  const int nbx = M >> 8;
  const int nwg = gridDim.x;
  const int orig = blockIdx.x;
  const int wg = (orig & 7) * (nwg >> 3) + (orig >> 3);
  const int m0 = (wg % nbx) << 8;
  const int n0 = (wg / nbx) << 8;

  const int trow = tid >> 3;
  const int tcsrc = (tid & 7) ^ (trow & 7);
  const ushort_t* gA[2][2];
  const ushort_t* gB[2][2];
#pragma unroll
  for (int h = 0; h < 2; ++h)
#pragma unroll
    for (int i = 0; i < 2; ++i){
      gA[h][i] = A  + (size_t)(m0 + h * 128 + i * 64 + trow) * lda + tcsrc * 8;
      gB[h][i] = BT + (size_t)(n0 + h * 128 + i * 64 + trow) * K   + tcsrc * 8;
    }

  auto STAGE_A = [&](int buf, int h, int kt){
    gl2lds16(gA[h][0] + (size_t)kt * 64, lds + buf * 32768 + h * 8192 + tid * 8);
    gl2lds16(gA[h][1] + (size_t)kt * 64, lds + buf * 32768 + h * 8192 + 4096 + tid * 8);
  };
  auto STAGE_B = [&](int buf, int h, int kt){
    gl2lds16(gB[h][0] + (size_t)kt * 64, lds + buf * 32768 + 16384 + h * 8192 + tid * 8);
    gl2lds16(gB[h][1] + (size_t)kt * 64, lds + buf * 32768 + 16384 + h * 8192 + 4096 + tid * 8);
  };

  const int ck0 = ((lhi) ^ (l15 & 7)) << 3;
  const int ck1 = ((4 + lhi) ^ (l15 & 7)) << 3;

  f32x4 acc[8][4] = {};
  bs8 aF[4][2], bLo[2][2], bHi[2][2];

  auto RDA = [&](int buf, int mq){
#pragma unroll
    for (int m = 0; m < 4; ++m){
      const ushort_t* r = lds + buf * 32768 + wr * 8192 + ((mq + m) * 16 + l15) * 64;
      aF[m][0] = *(const bs8*)(r + ck0);
      aF[m][1] = *(const bs8*)(r + ck1);
    }
  };
  auto RDB = [&](int buf, int nq, bs8 (&br)[2][2]){
#pragma unroll
    for (int n = 0; n < 2; ++n){
      const ushort_t* r = lds + buf * 32768 + 16384 + (wc >> 1) * 8192 +
                          ((wc & 1) * 64 + (nq + n) * 16 + l15) * 64;
      br[n][0] = *(const bs8*)(r + ck0);
      br[n][1] = *(const bs8*)(r + ck1);
    }
  };
  auto MMA = [&](int mq, int nq, bs8 (&br)[2][2]){
    __builtin_amdgcn_s_setprio(1);
#pragma unroll
    for (int m = 0; m < 4; ++m)
#pragma unroll
      for (int n = 0; n < 2; ++n){
        acc[mq + m][nq + n] = __builtin_amdgcn_mfma_f32_16x16x32_bf16(aF[m][0], br[n][0], acc[mq + m][nq + n], 0, 0, 0);
        acc[mq + m][nq + n] = __builtin_amdgcn_mfma_f32_16x16x32_bf16(aF[m][1], br[n][1], acc[mq + m][nq + n], 0, 0, 0);
      }
    __builtin_amdgcn_s_setprio(0);
  };

#define BAR() __builtin_amdgcn_s_barrier()
#define LGK() asm volatile("s_waitcnt lgkmcnt(0)" ::: "memory")
#define VMC4() asm volatile("s_waitcnt vmcnt(4)" ::: "memory")

  const int nkt = K >> 6;
  const int nIter = K >> 7;

  STAGE_A(0, 0, 0); STAGE_A(0, 1, 0); STAGE_B(0, 0, 0); STAGE_B(0, 1, 0);
  STAGE_B(1, 0, 1); STAGE_B(1, 1, 1);
  VMC4();
  BAR();

  for (int it = 0; it < nIter; ++it){
    const int kt1 = 2 * it + 1;
    int kt2 = 2 * it + 2; if (kt2 > nkt - 1) kt2 = nkt - 1;
    int kt3 = 2 * it + 3; if (kt3 > nkt - 1) kt3 = nkt - 1;
    RDA(0, 0); RDB(0, 0, bLo);
    STAGE_A(1, 0, kt1);
    BAR(); LGK(); MMA(0, 0, bLo); BAR();
    RDB(0, 2, bHi);
    STAGE_A(1, 1, kt1);
    BAR(); LGK(); MMA(0, 2, bHi); BAR();
    RDA(0, 4);
    STAGE_B(0, 0, kt2);
    BAR(); LGK(); MMA(4, 0, bLo); BAR();
    STAGE_B(0, 1, kt2);
    BAR(); LGK(); MMA(4, 2, bHi);
    VMC4(); BAR();
    RDA(1, 0); RDB(1, 0, bLo);
    STAGE_A(0, 0, kt2);
    BAR(); LGK(); MMA(0, 0, bLo); BAR();
    RDB(1, 2, bHi);
    STAGE_A(0, 1, kt2);
    BAR(); LGK(); MMA(0, 2, bHi); BAR();
    RDA(1, 4);
    STAGE_B(1, 0, kt3);
    BAR(); LGK(); MMA(4, 0, bLo); BAR();
    STAGE_B(1, 1, kt3);
    BAR(); LGK(); MMA(4, 2, bHi);
    VMC4(); BAR();
  }
#undef BAR
#undef LGK
#undef VMC4

#pragma unroll
  for (int m = 0; m < 8; ++m){
    const int r = m0 + wr * 128 + m * 16 + lhi * 4;
#pragma unroll
    for (int n = 0; n < 4; ++n){
      const int c = n0 + wc * 64 + n * 16 + l15;
#pragma unroll
      for (int j = 0; j < 4; ++j)
        st_out(C, (size_t)(r + j) * N + c, acc[m][n][j]);
    }
  }
}

// ============ flash attention v4: swapped QK^T + double-buffered K/V (T3-min) ============
// 4 waves x 32 q (QB=128). Q pre-scaled by 1/sqrt(192)*log2e. Counted vmcnt(10) pipeline.
__global__ __launch_bounds__(256, 2) void attn_kernel(const ushort_t* __restrict__ Qa,
                                                      const ushort_t* __restrict__ Ka,
                                                      const ushort_t* __restrict__ VT,
                                                      ushort_t* __restrict__ O){
  // [K0 12288 | K1 12288 | V0 8192 | V1 8192] elems = 80 KB
  __shared__ __align__(16) ushort_t lds[40960];
  const int tid = threadIdx.x, lane = tid & 63, wid = tid >> 6;
  const int bh = blockIdx.x;
  const int yy = blockIdx.y;
  const int qb = (yy < 8) ? (15 - yy) : (yy - 8);    // pair heavy+light per CU
  const int b = bh >> 4, h = bh & 15;
  const int qm0 = qb * 128;
  const int l15 = lane & 15, lhi = lane >> 4;

  // Q registers (pre-scaled): 2 q-groups of 16 rows, 6 k-chunks (B-fragment layout)
  bs8 qf[2][6];
#pragma unroll
  for (int qg = 0; qg < 2; ++qg){
    const size_t qrow = ((size_t)bh * 2048 + qm0 + wid * 32 + qg * 16 + l15) * 192;
#pragma unroll
    for (int kc = 0; kc < 6; ++kc)
      qf[qg][kc] = *(const bs8*)(Qa + qrow + kc * 32 + lhi * 8);
  }

  f32x4 acc[2][8] = {};
  float mrow[2] = {-1e30f, -1e30f};
  float lrow[2] = {0.f, 0.f};

  const ushort_t* Kbh = Ka + (size_t)bh * 2048 * 192;
  const ushort_t* Vbh = VT + (size_t)bh * 128 * 2048;

  // staging sources (inverse-swizzled global addresses, rule #21)
  const ushort_t* ksrc[6];
#pragma unroll
  for (int i = 0; i < 6; ++i){
    int c = i * 256 + tid;
    int row = c / 24, col = c % 24;
    int hk = (row & 3) | (((row >> 3) & 1) << 2);
    ksrc[i] = Kbh + (size_t)row * 192 + (col ^ hk) * 8;
  }
  const ushort_t* vsrc[4];
#pragma unroll
  for (int i = 0; i < 4; ++i){
    int c = i * 256 + tid;
    int d = c >> 3, col = c & 7;
    vsrc[i] = Vbh + (size_t)d * 2048 + (col ^ (d & 7)) * 8;
  }

  auto STAGE = [&](int kt, int buf){
#pragma unroll
    for (int i = 0; i < 6; ++i)
      gl2lds16(ksrc[i] + (size_t)kt * 12288, lds + buf * 12288 + (i * 256 + tid) * 8);
#pragma unroll
    for (int i = 0; i < 4; ++i)
      gl2lds16(vsrc[i] + kt * 64, lds + 24576 + buf * 8192 + (i * 256 + tid) * 8);
  };

  const int nkt = 2 * qb + 2;
  const int mylast = (qm0 + wid * 32 + 31) >> 6;
  const int hkr = (l15 & 3) | (((l15 >> 2) & 1) << 2);  // read-side K hash

#define BARR() __builtin_amdgcn_s_barrier()
#define LGK0() asm volatile("s_waitcnt lgkmcnt(0)" ::: "memory")
#define VMC(n) asm volatile("s_waitcnt vmcnt(" #n ")" ::: "memory")

  STAGE(0, 0);
  STAGE(1, 1);
  VMC(10);
  BARR();

  for (int kt = 0; kt < nkt; ++kt){
    const int cur = kt & 1;
    const ushort_t* Kb = lds + cur * 12288;
    const ushort_t* Vb = lds + 24576 + cur * 8192;

    if (kt <= mylast){
      // S^T = K x Q^T: per MFMA m, A-row r holds physical kv pi(m,r)
      f32x4 s[2][4] = {};
#pragma unroll
      for (int kc = 0; kc < 6; ++kc){
        bs8 kf4[4];
#pragma unroll
        for (int m = 0; m < 4; ++m){
          int row = ((m >> 1) << 5) + ((l15 >> 2) << 3) + ((m & 1) << 2) + (l15 & 3);
          kf4[m] = *(const bs8*)(Kb + row * 192 + (((kc * 4 + lhi) ^ hkr) << 3));
        }
#pragma unroll
        for (int qg = 0; qg < 2; ++qg)
#pragma unroll
          for (int m = 0; m < 4; ++m)
            s[qg][m] = __builtin_amdgcn_mfma_f32_16x16x32_bf16(kf4[m], qf[qg][kc], s[qg][m], 0, 0, 0);
      }

      // per-lane online softmax (lane owns ONE q per group); defer-max THR=8
      const bool noMask = (kt * 64 + 63) <= (qm0 + wid * 32);   // wave-uniform
#pragma unroll
      for (int qg = 0; qg < 2; ++qg){
        const int qi = qm0 + wid * 32 + qg * 16 + l15;
        float rmax = -3e38f;
#pragma unroll
        for (int m = 0; m < 4; ++m)
#pragma unroll
          for (int j = 0; j < 4; ++j){
            float sv = s[qg][m][j];
            if (!noMask){
              int ki = kt * 64 + ((m >> 1) << 5) + (lhi << 3) + ((m & 1) << 2) + j;
              if (ki > qi) sv = -3e38f;
            }
            s[qg][m][j] = sv;
            rmax = fmaxf(rmax, sv);
          }
        rmax = fmaxf(rmax, __shfl_xor(rmax, 16));
        rmax = fmaxf(rmax, __shfl_xor(rmax, 32));
        if (!__all(rmax <= mrow[qg] + 8.f)){
          float mnew = fmaxf(mrow[qg], rmax);
          float osc = exp2f(mrow[qg] - mnew);
          lrow[qg] *= osc;
#pragma unroll
          for (int f = 0; f < 8; ++f) acc[qg][f] *= osc;
          mrow[qg] = mnew;
        }
        float rsum = 0.f;
#pragma unroll
        for (int m = 0; m < 4; ++m)
#pragma unroll
          for (int j = 0; j < 4; ++j){
            float pv = exp2f(s[qg][m][j] - mrow[qg]);
            s[qg][m][j] = pv;
            rsum += pv;
          }
        rsum += __shfl_xor(rsum, 16);
        rsum += __shfl_xor(rsum, 32);
        lrow[qg] += rsum;
      }

      // pack P in-register via v_cvt_pk_bf16_f32 (T12)
      bs8 pb[2][2];
#pragma unroll
      for (int qg = 0; qg < 2; ++qg)
#pragma unroll
        for (int kc2 = 0; kc2 < 2; ++kc2){
          union { bs8 v; unsigned u[4]; } pu;
#pragma unroll
          for (int half = 0; half < 2; ++half){
            const f32x4& sv = s[qg][2 * kc2 + half];
            pu.u[2 * half]     = cvt_pk_bf16(sv[0], sv[1]);
            pu.u[2 * half + 1] = cvt_pk_bf16(sv[2], sv[3]);
          }
          pb[qg][kc2] = pu.v;
        }

      // O^T += V^T x P^T
#pragma unroll
      for (int kc2 = 0; kc2 < 2; ++kc2)
#pragma unroll
        for (int f = 0; f < 8; ++f){
          bs8 vf = *(const bs8*)(Vb + (f * 16 + l15) * 64 + (((kc2 * 4 + lhi) ^ (l15 & 7)) << 3));
#pragma unroll
          for (int qg = 0; qg < 2; ++qg)
            acc[qg][f] = __builtin_amdgcn_mfma_f32_16x16x32_bf16(vf, pb[qg][kc2], acc[qg][f], 0, 0, 0);
        }
    }

    LGK0();            // this wave's LDS reads done
    BARR();            // all waves done reading buf[cur]
    if (kt + 2 < nkt){
      STAGE(kt + 2, cur);
      VMC(10);         // kt+1's 10 loads (oldest) landed; kt+2's may fly
    } else {
      VMC(0);
    }
    BARR();            // buf[cur^1] (tile kt+1) visible to all
  }
#undef BARR
#undef LGK0
#undef VMC

  // epilogue
#pragma unroll
  for (int qg = 0; qg < 2; ++qg){
    float rl = 1.0f / lrow[qg];
    int t = qm0 + wid * 32 + qg * 16 + l15;
#pragma unroll
    for (int f = 0; f < 8; ++f){
      u16x4 o;
#pragma unroll
      for (int j = 0; j < 4; ++j) o[j] = f2bf(acc[qg][f][j] * rl);
      *(u16x4*)(O + ((size_t)b * 2048 + t) * 2048 + h * 128 + f * 16 + lhi * 4) = o;
    }
  }
}

extern "C" void kernel_launch(void* const* d_in, const int* in_sizes, int n_in,
                              void* d_out, int out_size, void* d_ws, size_t ws_size,
                              hipStream_t stream){
  constexpr int Bc = 2, Tc = 2048, Cc = 2048, Hc = 16, HDc = 128, RDc = 64, KVRc = 512, QRc = 1024;
  constexpr int Mx = Bc * Tc; // 4096
  const float* x     = (const float*)d_in[0];
  const float* w_dq  = (const float*)d_in[1];
  const float* w_uq  = (const float*)d_in[2];
  const float* w_dkv = (const float*)d_in[3];
  const float* w_uk  = (const float*)d_in[4];
  const float* w_uv  = (const float*)d_in[5];
  const float* w_qr  = (const float*)d_in[6];
  const float* w_kr  = (const float*)d_in[7];
  const float* w_o   = (const float*)d_in[8];
  const float* fc    = (const float*)d_in[9];
  const float* fs    = (const float*)d_in[10];
  float* out = (float*)d_out;

  char* ws = (char*)d_ws;
  size_t off = 0;
  auto alloc = [&](size_t elems) -> ushort_t* {
    ushort_t* p = (ushort_t*)(ws + off);
    off += ((elems * 2) + 255) & ~(size_t)255;
    return p;
  };
  ushort_t* xb    = alloc((size_t)Mx * Cc);
  ushort_t* wdqT  = alloc((size_t)QRc * Cc);
  ushort_t* wdkvT = alloc((size_t)KVRc * Cc);
  ushort_t* wkrT  = alloc((size_t)(Hc * RDc) * Cc);
  ushort_t* wuqT  = alloc((size_t)(Hc * HDc) * QRc);
  ushort_t* wqrT  = alloc((size_t)(Hc * RDc) * QRc);
  ushort_t* wukT  = alloc((size_t)(Hc * HDc) * KVRc);
  ushort_t* wuvT  = alloc((size_t)(Hc * HDc) * KVRc);
  ushort_t* woT   = alloc((size_t)Cc * (Hc * HDc));
  ushort_t* comb1 = alloc((size_t)Mx * 2560);   // [cq | ckv | kr]
  ushort_t* qcomb = alloc((size_t)Mx * 3072);   // [qc | qr]
  ushort_t* kvcomb= alloc((size_t)Mx * 4096);   // [kc | v]
  ushort_t* Qa    = alloc((size_t)Bc * Hc * Tc * 192);
  ushort_t* Ka    = alloc((size_t)Bc * Hc * Tc * 192);
  ushort_t* vT    = alloc((size_t)Bc * Hc * HDc * Tc);
  ushort_t* O     = xb;  // alias: xb dead after GEMM1

  const float scale2 = 0.07216878364870323f * 1.4426950408889634f; // 1/sqrt(192)*log2e

  cast_x<<<dim3(((size_t)Mx * Cc) / 1024), 256, 0, stream>>>(x, xb);

  transpose_cast<<<dim3(QRc / 32, Cc / 32), dim3(32, 8), 0, stream>>>(w_dq, wdqT, Cc, QRc);
  transpose_cast<<<dim3(KVRc / 32, Cc / 32), dim3(32, 8), 0, stream>>>(w_dkv, wdkvT, Cc, KVRc);
  transpose_cast<<<dim3((Hc * RDc) / 32, Cc / 32), dim3(32, 8), 0, stream>>>(w_kr, wkrT, Cc, Hc * RDc);
  transpose_cast<<<dim3((Hc * HDc) / 32, QRc / 32), dim3(32, 8), 0, stream>>>(w_uq, wuqT, QRc, Hc * HDc);
  transpose_cast<<<dim3((Hc * RDc) / 32, QRc / 32), dim3(32, 8), 0, stream>>>(w_qr, wqrT, QRc, Hc * RDc);
  transpose_cast<<<dim3((Hc * HDc) / 32, KVRc / 32), dim3(32, 8), 0, stream>>>(w_uk, wukT, KVRc, Hc * HDc);
  transpose_cast<<<dim3((Hc * HDc) / 32, KVRc / 32), dim3(32, 8), 0, stream>>>(w_uv, wuvT, KVRc, Hc * HDc);
  transpose_cast<<<dim3(Cc / 32, (Hc * HDc) / 32), dim3(32, 8), 0, stream>>>(w_o, woT, Hc * HDc, Cc);

  gemm256<ushort_t><<<dim3((Mx / 256) * (2560 / 256)), 512, 0, stream>>>(xb, Cc, wdqT, comb1, Mx, 2560, Cc);
  gemm256<ushort_t><<<dim3((Mx / 256) * (3072 / 256)), 512, 0, stream>>>(comb1, 2560, wuqT, qcomb, Mx, 3072, QRc);
  gemm256<ushort_t><<<dim3((Mx / 256) * (4096 / 256)), 512, 0, stream>>>(comb1 + QRc, 2560, wukT, kvcomb, Mx, 4096, KVRc);

  assemble_qk<<<Mx, 256, 0, stream>>>(qcomb, 3072, qcomb + 2048, 3072, fc, fs, Qa, scale2);
  assemble_qk<<<Mx, 256, 0, stream>>>(kvcomb, 4096, comb1 + 1536, 2560, fc, fs, Ka, 1.0f);
  transpose_v<<<dim3(Tc / 32, HDc / 32, Bc * Hc), dim3(32, 8), 0, stream>>>(kvcomb + 2048, 4096, vT);

  attn_kernel<<<dim3(Bc * Hc, 16), 256, 0, stream>>>(Qa, Ka, vT, O);

  gemm256<float><<<dim3((Mx / 256) * (Cc / 256)), 512, 0, stream>>>(O, Hc * HDc, woT, out, Mx, Cc, Hc * HDc);
}

// Round 6
// 317.343 us; speedup vs baseline: 1.9653x; 1.0869x over previous
//
#include <hip/hip_runtime.h>

typedef unsigned short ushort_t;
typedef __attribute__((ext_vector_type(8))) short bs8;       // 8 x bf16 (4 VGPR)
typedef __attribute__((ext_vector_type(4))) float f32x4;
typedef __attribute__((ext_vector_type(4))) unsigned short u16x4;

#define DEV __device__ __forceinline__

DEV unsigned short f2bf(float f){
  unsigned u = __float_as_uint(f);
  u += 0x7fffu + ((u >> 16) & 1u);           // round-to-nearest-even
  return (unsigned short)(u >> 16);
}
DEV float bf2f(unsigned short h){ return __uint_as_float(((unsigned)h) << 16); }

DEV unsigned cvt_pk_bf16(float lo, float hi){
  unsigned r;
  asm volatile("v_cvt_pk_bf16_f32 %0, %1, %2" : "=v"(r) : "v"(lo), "v"(hi));
  return r;
}

DEV void gl2lds16(const void* g, void* l){
  __builtin_amdgcn_global_load_lds((const __attribute__((address_space(1))) void*)g,
                                   (__attribute__((address_space(3))) void*)l, 16, 0, 0);
}

DEV void st_out(ushort_t* C, size_t i, float v){ C[i] = f2bf(v); }
DEV void st_out(float*    C, size_t i, float v){ C[i] = v; }

// ---------------- cast x (fp32 -> bf16), 4 elems/thread ----------------
__global__ __launch_bounds__(256) void cast_x(const float* __restrict__ in,
                                              ushort_t* __restrict__ outb){
  size_t i = ((size_t)blockIdx.x * 256 + threadIdx.x) * 4;
  float4 v = *(const float4*)(in + i);
  u16x4 o;
  o[0] = f2bf(v.x); o[1] = f2bf(v.y); o[2] = f2bf(v.z); o[3] = f2bf(v.w);
  *(u16x4*)(outb + i) = o;
}

// ---------------- transpose-cast weight: in[K][N] fp32 -> out[N][K] bf16 ----------------
__global__ __launch_bounds__(256) void transpose_cast(const float* __restrict__ in,
                                                      ushort_t* __restrict__ out,
                                                      int K, int N){
  __shared__ float tile[32][33];
  int k0 = blockIdx.y * 32, n0 = blockIdx.x * 32;
  int tx = threadIdx.x, ty = threadIdx.y;
  for (int r = ty; r < 32; r += 8)
    tile[r][tx] = in[(size_t)(k0 + r) * N + n0 + tx];
  __syncthreads();
  for (int r = ty; r < 32; r += 8)
    out[(size_t)(n0 + r) * K + k0 + tx] = f2bf(tile[tx][r]);
}

// ---------------- bf16 transpose per (b,h): v[M][ldv] -> vT[BH][128][T] ----------------
__global__ __launch_bounds__(256) void transpose_v(const ushort_t* __restrict__ v, int ldv,
                                                   ushort_t* __restrict__ vT){
  __shared__ ushort_t tile[32][33];
  int bh = blockIdx.z; int b = bh >> 4, h = bh & 15;
  int t0 = blockIdx.x * 32, d0 = blockIdx.y * 32;
  int tx = threadIdx.x, ty = threadIdx.y;
  for (int r = ty; r < 32; r += 8)
    tile[r][tx] = v[((size_t)(b * 2048 + t0 + r)) * ldv + h * 128 + d0 + tx];
  __syncthreads();
  for (int r = ty; r < 32; r += 8)
    vT[((size_t)bh * 128 + d0 + r) * 2048 + t0 + tx] = tile[tx][r];
}

// ================= 256x256 8-phase GEMM (T2+T3+T4+T5), BK=64 =================
// EPI 0: plain C[M][N] (OT). EPI 1: GEMM1 -> comb1[4096][1536] + rope(kr)->Ka.
// EPI 2: GEMM2 -> Qa (qc + rope(qr)), pre-scaled. EPI 3: GEMM3 -> Ka(kc) + vb(C).
template<int EPI, typename OT>
__global__ __launch_bounds__(512, 2) void gemm256(const ushort_t* __restrict__ A, int lda,
                                                  const ushort_t* __restrict__ BT,
                                                  OT* __restrict__ C,
                                                  int M, int N, int K,
                                                  ushort_t* __restrict__ aux,
                                                  const float* __restrict__ fcp,
                                                  const float* __restrict__ fsp){
  __shared__ __align__(16) ushort_t lds[65536];   // 128 KiB
  const int tid = threadIdx.x, lane = tid & 63, wid = tid >> 6;
  const int l15 = lane & 15, lhi = lane >> 4;
  const int wr = wid >> 2, wc = wid & 3;

  const int nbx = M >> 8;
  const int nwg = gridDim.x;
  const int orig = blockIdx.x;
  const int wg = (orig & 7) * (nwg >> 3) + (orig >> 3);
  const int m0 = (wg % nbx) << 8;
  const int n0 = (wg / nbx) << 8;

  const int trow = tid >> 3;
  const int tcsrc = (tid & 7) ^ (trow & 7);
  const ushort_t* gA[2][2];
  const ushort_t* gB[2][2];
#pragma unroll
  for (int h = 0; h < 2; ++h)
#pragma unroll
    for (int i = 0; i < 2; ++i){
      gA[h][i] = A  + (size_t)(m0 + h * 128 + i * 64 + trow) * lda + tcsrc * 8;
      gB[h][i] = BT + (size_t)(n0 + h * 128 + i * 64 + trow) * K   + tcsrc * 8;
    }

  auto STAGE_A = [&](int buf, int h, int kt){
    gl2lds16(gA[h][0] + (size_t)kt * 64, lds + buf * 32768 + h * 8192 + tid * 8);
    gl2lds16(gA[h][1] + (size_t)kt * 64, lds + buf * 32768 + h * 8192 + 4096 + tid * 8);
  };
  auto STAGE_B = [&](int buf, int h, int kt){
    gl2lds16(gB[h][0] + (size_t)kt * 64, lds + buf * 32768 + 16384 + h * 8192 + tid * 8);
    gl2lds16(gB[h][1] + (size_t)kt * 64, lds + buf * 32768 + 16384 + h * 8192 + 4096 + tid * 8);
  };

  const int ck0 = ((lhi) ^ (l15 & 7)) << 3;
  const int ck1 = ((4 + lhi) ^ (l15 & 7)) << 3;

  f32x4 acc[8][4] = {};
  bs8 aF[4][2], bLo[2][2], bHi[2][2];

  auto RDA = [&](int buf, int mq){
#pragma unroll
    for (int m = 0; m < 4; ++m){
      const ushort_t* r = lds + buf * 32768 + wr * 8192 + ((mq + m) * 16 + l15) * 64;
      aF[m][0] = *(const bs8*)(r + ck0);
      aF[m][1] = *(const bs8*)(r + ck1);
    }
  };
  auto RDB = [&](int buf, int nq, bs8 (&br)[2][2]){
#pragma unroll
    for (int n = 0; n < 2; ++n){
      const ushort_t* r = lds + buf * 32768 + 16384 + (wc >> 1) * 8192 +
                          ((wc & 1) * 64 + (nq + n) * 16 + l15) * 64;
      br[n][0] = *(const bs8*)(r + ck0);
      br[n][1] = *(const bs8*)(r + ck1);
    }
  };
  auto MMA = [&](int mq, int nq, bs8 (&br)[2][2]){
    __builtin_amdgcn_s_setprio(1);
#pragma unroll
    for (int m = 0; m < 4; ++m)
#pragma unroll
      for (int n = 0; n < 2; ++n){
        acc[mq + m][nq + n] = __builtin_amdgcn_mfma_f32_16x16x32_bf16(aF[m][0], br[n][0], acc[mq + m][nq + n], 0, 0, 0);
        acc[mq + m][nq + n] = __builtin_amdgcn_mfma_f32_16x16x32_bf16(aF[m][1], br[n][1], acc[mq + m][nq + n], 0, 0, 0);
      }
    __builtin_amdgcn_s_setprio(0);
  };

#define BAR() __builtin_amdgcn_s_barrier()
#define LGK() asm volatile("s_waitcnt lgkmcnt(0)" ::: "memory")
#define VMC4() asm volatile("s_waitcnt vmcnt(4)" ::: "memory")

  const int nkt = K >> 6;
  const int nIter = K >> 7;

  STAGE_A(0, 0, 0); STAGE_A(0, 1, 0); STAGE_B(0, 0, 0); STAGE_B(0, 1, 0);
  STAGE_B(1, 0, 1); STAGE_B(1, 1, 1);
  VMC4();
  BAR();

  for (int it = 0; it < nIter; ++it){
    const int kt1 = 2 * it + 1;
    int kt2 = 2 * it + 2; if (kt2 > nkt - 1) kt2 = nkt - 1;
    int kt3 = 2 * it + 3; if (kt3 > nkt - 1) kt3 = nkt - 1;
    RDA(0, 0); RDB(0, 0, bLo);
    STAGE_A(1, 0, kt1);
    BAR(); LGK(); MMA(0, 0, bLo); BAR();
    RDB(0, 2, bHi);
    STAGE_A(1, 1, kt1);
    BAR(); LGK(); MMA(0, 2, bHi); BAR();
    RDA(0, 4);
    STAGE_B(0, 0, kt2);
    BAR(); LGK(); MMA(4, 0, bLo); BAR();
    STAGE_B(0, 1, kt2);
    BAR(); LGK(); MMA(4, 2, bHi);
    VMC4(); BAR();
    RDA(1, 0); RDB(1, 0, bLo);
    STAGE_A(0, 0, kt2);
    BAR(); LGK(); MMA(0, 0, bLo); BAR();
    RDB(1, 2, bHi);
    STAGE_A(0, 1, kt2);
    BAR(); LGK(); MMA(0, 2, bHi); BAR();
    RDA(1, 4);
    STAGE_B(1, 0, kt3);
    BAR(); LGK(); MMA(4, 0, bLo); BAR();
    STAGE_B(1, 1, kt3);
    BAR(); LGK(); MMA(4, 2, bHi);
    VMC4(); BAR();
  }
#undef BAR
#undef LGK
#undef VMC4

  // ---- epilogue ----
  const float SC = (EPI == 2) ? (0.07216878364870323f * 1.4426950408889634f) : 1.0f;
  const int RBASE = (EPI == 1) ? 1536 : 2048;     // rope-region start col
#pragma unroll
  for (int m = 0; m < 8; ++m){
    const int r = m0 + wr * 128 + m * 16 + lhi * 4;
#pragma unroll
    for (int n = 0; n < 4; ++n){
      const int c = n0 + wc * 64 + n * 16 + l15;
      if (EPI == 0){
#pragma unroll
        for (int j = 0; j < 4; ++j)
          st_out(C, (size_t)(r + j) * N + c, acc[m][n][j]);
      } else if ((EPI == 1 && c < 1536)){
#pragma unroll
        for (int j = 0; j < 4; ++j)
          C[(size_t)(r + j) * 1536 + c] = (OT)f2bf(acc[m][n][j]);
      } else if (EPI == 2 && c < 2048){
        int hh = c >> 7, d = c & 127;
#pragma unroll
        for (int j = 0; j < 4; ++j){
          int rr = r + j, bb = rr >> 11, tt = rr & 2047;
          aux[((size_t)(bb * 16 + hh) * 2048 + tt) * 192 + d] = f2bf(acc[m][n][j] * SC);
        }
      } else if (EPI == 3 && c < 2048){
        int hh = c >> 7, d = c & 127;
#pragma unroll
        for (int j = 0; j < 4; ++j){
          int rr = r + j, bb = rr >> 11, tt = rr & 2047;
          aux[((size_t)(bb * 16 + hh) * 2048 + tt) * 192 + d] = f2bf(acc[m][n][j]);
        }
      } else if (EPI == 3){
        // v region -> vb[M][2048]
#pragma unroll
        for (int j = 0; j < 4; ++j)
          C[(size_t)(r + j) * 2048 + (c - 2048)] = (OT)f2bf(acc[m][n][j]);
      } else {
        // rope region (EPI 1 or 2): pairs are adjacent cols = partner lane
        int cr = c - RBASE;
        int hh = cr >> 6, dr = cr & 63, ii = dr >> 1;
#pragma unroll
        for (int j = 0; j < 4; ++j){
          int rr = r + j, bb = rr >> 11, tt = rr & 2047;
          float v = acc[m][n][j] * SC;
          float pv = __shfl_xor(v, 1);
          float co = fcp[tt * 32 + ii], si = fsp[tt * 32 + ii];
          float o = (l15 & 1) ? fmaf(pv, si, v * co) : fmaf(-pv, si, v * co);
          aux[((size_t)(bb * 16 + hh) * 2048 + tt) * 192 + 128 + dr] = f2bf(o);
        }
      }
    }
  }
}

// ====== flash attention v5: 8 waves x 16q, two uniform q-tiles per block ======
// grid (32 bh, 8 p); block handles qb=15-p then qb=p: 34 tile-units for ALL blocks.
__global__ __launch_bounds__(512, 1) void attn_kernel(const ushort_t* __restrict__ Qa,
                                                      const ushort_t* __restrict__ Ka,
                                                      const ushort_t* __restrict__ VT,
                                                      ushort_t* __restrict__ O){
  // [K0 12288 | K1 12288 | V0 8192 | V1 8192] elems = 80 KB
  __shared__ __align__(16) ushort_t lds[40960];
  const int tid = threadIdx.x, lane = tid & 63, wid = tid >> 6;
  const int bh = blockIdx.x, p = blockIdx.y;
  const int b = bh >> 4, h = bh & 15;
  const int qb0 = 15 - p, qb1 = p;
  const int nkt0 = 2 * qb0 + 2;
  const int NT = 34;
  const int l15 = lane & 15, lhi = lane >> 4;

  const ushort_t* Kbh = Ka + (size_t)bh * 2048 * 192;
  const ushort_t* Vbh = VT + (size_t)bh * 128 * 2048;

  // staging sources (inverse-swizzled global addresses, rule #21); 512-thread split
  const ushort_t* ksrc[3];
#pragma unroll
  for (int i = 0; i < 3; ++i){
    int c = i * 512 + tid;
    int row = c / 24, col = c % 24;
    int hk = (row & 3) | (((row >> 3) & 1) << 2);
    ksrc[i] = Kbh + (size_t)row * 192 + (col ^ hk) * 8;
  }
  const ushort_t* vsrc[2];
#pragma unroll
  for (int i = 0; i < 2; ++i){
    int c = i * 512 + tid;
    int d = c >> 3, col = c & 7;
    vsrc[i] = Vbh + (size_t)d * 2048 + (col ^ (d & 7)) * 8;
  }

  auto STAGE = [&](int ft, int buf){
    int kt = (ft < nkt0) ? ft : ft - nkt0;
#pragma unroll
    for (int i = 0; i < 3; ++i)
      gl2lds16(ksrc[i] + (size_t)kt * 12288, lds + buf * 12288 + (i * 512 + tid) * 8);
#pragma unroll
    for (int i = 0; i < 2; ++i)
      gl2lds16(vsrc[i] + kt * 64, lds + 24576 + buf * 8192 + (i * 512 + tid) * 8);
  };

  bs8 qf[6];
  auto LOADQ = [&](int qb){
    const size_t qrow = ((size_t)bh * 2048 + qb * 128 + wid * 16 + l15) * 192;
#pragma unroll
    for (int kc = 0; kc < 6; ++kc)
      qf[kc] = *(const bs8*)(Qa + qrow + kc * 32 + lhi * 8);
  };

  f32x4 acc[8] = {};
  float mrow = -1e30f, lrow = 0.f;

  auto EPI = [&](int qb){
    float rl = 1.0f / lrow;
    int t = qb * 128 + wid * 16 + l15;
#pragma unroll
    for (int f = 0; f < 8; ++f){
      u16x4 o;
#pragma unroll
      for (int j = 0; j < 4; ++j) o[j] = f2bf(acc[f][j] * rl);
      *(u16x4*)(O + ((size_t)b * 2048 + t) * 2048 + h * 128 + f * 16 + lhi * 4) = o;
    }
  };

  const int hkr = (l15 & 3) | (((l15 >> 2) & 1) << 2);

#define BARR() __builtin_amdgcn_s_barrier()
#define LGK0() asm volatile("s_waitcnt lgkmcnt(0)" ::: "memory")
#define VMC(n) asm volatile("s_waitcnt vmcnt(" #n ")" ::: "memory")

  LOADQ(qb0);
  STAGE(0, 0);
  STAGE(1, 1);
  VMC(5);
  BARR();

  for (int ft = 0; ft < NT; ++ft){
    if (ft == nkt0){
      EPI(qb0);
#pragma unroll
      for (int f = 0; f < 8; ++f) acc[f] = (f32x4){0.f, 0.f, 0.f, 0.f};
      mrow = -1e30f; lrow = 0.f;
      LOADQ(qb1);
    }
    const int seg = (ft >= nkt0) ? 1 : 0;
    const int kt = seg ? ft - nkt0 : ft;
    const int qb = seg ? qb1 : qb0;
    const int qm0 = qb << 7;
    const int mylast = 2 * qb + (wid >> 2);
    const int cur = ft & 1;
    const ushort_t* Kb = lds + cur * 12288;
    const ushort_t* Vb = lds + 24576 + cur * 8192;

    if (kt <= mylast){
      // S^T = K x Q^T (permuted kv->A-row mapping)
      f32x4 s[4] = {};
      __builtin_amdgcn_s_setprio(1);
#pragma unroll
      for (int kc = 0; kc < 6; ++kc){
        bs8 kf4[4];
#pragma unroll
        for (int m = 0; m < 4; ++m){
          int row = ((m >> 1) << 5) + ((l15 >> 2) << 3) + ((m & 1) << 2) + (l15 & 3);
          kf4[m] = *(const bs8*)(Kb + row * 192 + (((kc * 4 + lhi) ^ hkr) << 3));
        }
#pragma unroll
        for (int m = 0; m < 4; ++m)
          s[m] = __builtin_amdgcn_mfma_f32_16x16x32_bf16(kf4[m], qf[kc], s[m], 0, 0, 0);
      }
      __builtin_amdgcn_s_setprio(0);

      // per-lane online softmax (lane owns ONE q); defer-max THR=8
      const bool noMask = (kt * 64 + 63) <= (qm0 + wid * 16);
      const int qi = qm0 + wid * 16 + l15;
      float rmax = -3e38f;
#pragma unroll
      for (int m = 0; m < 4; ++m)
#pragma unroll
        for (int j = 0; j < 4; ++j){
          float sv = s[m][j];
          if (!noMask){
            int ki = kt * 64 + ((m >> 1) << 5) + (lhi << 3) + ((m & 1) << 2) + j;
            if (ki > qi) sv = -3e38f;
          }
          s[m][j] = sv;
          rmax = fmaxf(rmax, sv);
        }
      rmax = fmaxf(rmax, __shfl_xor(rmax, 16));
      rmax = fmaxf(rmax, __shfl_xor(rmax, 32));
      if (!__all(rmax <= mrow + 8.f)){
        float mnew = fmaxf(mrow, rmax);
        float osc = exp2f(mrow - mnew);
        lrow *= osc;
#pragma unroll
        for (int f = 0; f < 8; ++f) acc[f] *= osc;
        mrow = mnew;
      }
      float rsum = 0.f;
#pragma unroll
      for (int m = 0; m < 4; ++m)
#pragma unroll
        for (int j = 0; j < 4; ++j){
          float pv = exp2f(s[m][j] - mrow);
          s[m][j] = pv;
          rsum += pv;
        }
      rsum += __shfl_xor(rsum, 16);
      rsum += __shfl_xor(rsum, 32);
      lrow += rsum;

      // pack P in-register via v_cvt_pk_bf16_f32 (T12)
      bs8 pb[2];
#pragma unroll
      for (int kc2 = 0; kc2 < 2; ++kc2){
        union { bs8 v; unsigned u[4]; } pu;
#pragma unroll
        for (int half = 0; half < 2; ++half){
          const f32x4& sv = s[2 * kc2 + half];
          pu.u[2 * half]     = cvt_pk_bf16(sv[0], sv[1]);
          pu.u[2 * half + 1] = cvt_pk_bf16(sv[2], sv[3]);
        }
        pb[kc2] = pu.v;
      }

      // O^T += V^T x P^T
      __builtin_amdgcn_s_setprio(1);
#pragma unroll
      for (int kc2 = 0; kc2 < 2; ++kc2)
#pragma unroll
        for (int f = 0; f < 8; ++f){
          bs8 vf = *(const bs8*)(Vb + (f * 16 + l15) * 64 + (((kc2 * 4 + lhi) ^ (l15 & 7)) << 3));
          acc[f] = __builtin_amdgcn_mfma_f32_16x16x32_bf16(vf, pb[kc2], acc[f], 0, 0, 0);
        }
      __builtin_amdgcn_s_setprio(0);
    }

    LGK0();
    BARR();
    if (ft + 2 < NT){
      STAGE(ft + 2, cur);
      VMC(5);
    } else {
      VMC(0);
    }
    BARR();
  }
#undef BARR
#undef LGK0
#undef VMC

  EPI(qb1);
}

extern "C" void kernel_launch(void* const* d_in, const int* in_sizes, int n_in,
                              void* d_out, int out_size, void* d_ws, size_t ws_size,
                              hipStream_t stream){
  constexpr int Bc = 2, Tc = 2048, Cc = 2048, Hc = 16, HDc = 128, RDc = 64, KVRc = 512, QRc = 1024;
  constexpr int Mx = Bc * Tc; // 4096
  const float* x     = (const float*)d_in[0];
  const float* w_dq  = (const float*)d_in[1];
  const float* w_uq  = (const float*)d_in[2];
  const float* w_dkv = (const float*)d_in[3];
  const float* w_uk  = (const float*)d_in[4];
  const float* w_uv  = (const float*)d_in[5];
  const float* w_qr  = (const float*)d_in[6];
  const float* w_kr  = (const float*)d_in[7];
  const float* w_o   = (const float*)d_in[8];
  const float* fc    = (const float*)d_in[9];
  const float* fs    = (const float*)d_in[10];
  float* out = (float*)d_out;

  char* ws = (char*)d_ws;
  size_t off = 0;
  auto alloc = [&](size_t elems) -> ushort_t* {
    ushort_t* p = (ushort_t*)(ws + off);
    off += ((elems * 2) + 255) & ~(size_t)255;
    return p;
  };
  ushort_t* xb    = alloc((size_t)Mx * Cc);
  // GEMM1 BT group (adjacent): [wdq 1024 | wdkv 512 | wkr 1024] rows, K=2048
  ushort_t* wdqT  = alloc((size_t)QRc * Cc);
  ushort_t* wdkvT = alloc((size_t)KVRc * Cc);
  ushort_t* wkrT  = alloc((size_t)(Hc * RDc) * Cc);
  // GEMM2 BT group: [wuq 2048 | wqr 1024] rows, K=1024
  ushort_t* wuqT  = alloc((size_t)(Hc * HDc) * QRc);
  ushort_t* wqrT  = alloc((size_t)(Hc * RDc) * QRc);
  // GEMM3 BT group: [wuk 2048 | wuv 2048] rows, K=512
  ushort_t* wukT  = alloc((size_t)(Hc * HDc) * KVRc);
  ushort_t* wuvT  = alloc((size_t)(Hc * HDc) * KVRc);
  ushort_t* woT   = alloc((size_t)Cc * (Hc * HDc));
  ushort_t* comb1 = alloc((size_t)Mx * 1536);   // [cq 1024 | ckv 512]
  ushort_t* vb    = alloc((size_t)Mx * 2048);   // v (pre-transpose)
  ushort_t* Qa    = alloc((size_t)Bc * Hc * Tc * 192);
  ushort_t* Ka    = alloc((size_t)Bc * Hc * Tc * 192);
  ushort_t* vT    = alloc((size_t)Bc * Hc * HDc * Tc);
  ushort_t* O     = xb;  // alias: xb dead after GEMM1

  cast_x<<<dim3(((size_t)Mx * Cc) / 1024), 256, 0, stream>>>(x, xb);

  transpose_cast<<<dim3(QRc / 32, Cc / 32), dim3(32, 8), 0, stream>>>(w_dq, wdqT, Cc, QRc);
  transpose_cast<<<dim3(KVRc / 32, Cc / 32), dim3(32, 8), 0, stream>>>(w_dkv, wdkvT, Cc, KVRc);
  transpose_cast<<<dim3((Hc * RDc) / 32, Cc / 32), dim3(32, 8), 0, stream>>>(w_kr, wkrT, Cc, Hc * RDc);
  transpose_cast<<<dim3((Hc * HDc) / 32, QRc / 32), dim3(32, 8), 0, stream>>>(w_uq, wuqT, QRc, Hc * HDc);
  transpose_cast<<<dim3((Hc * RDc) / 32, QRc / 32), dim3(32, 8), 0, stream>>>(w_qr, wqrT, QRc, Hc * RDc);
  transpose_cast<<<dim3((Hc * HDc) / 32, KVRc / 32), dim3(32, 8), 0, stream>>>(w_uk, wukT, KVRc, Hc * HDc);
  transpose_cast<<<dim3((Hc * HDc) / 32, KVRc / 32), dim3(32, 8), 0, stream>>>(w_uv, wuvT, KVRc, Hc * HDc);
  transpose_cast<<<dim3(Cc / 32, (Hc * HDc) / 32), dim3(32, 8), 0, stream>>>(w_o, woT, Hc * HDc, Cc);

  // GEMM1: x @ [w_dq|w_dkv|w_kr] -> comb1[.][1536] + rope(kr)->Ka[..][128..192)
  gemm256<1, ushort_t><<<dim3((Mx / 256) * (2560 / 256)), 512, 0, stream>>>(
      xb, Cc, wdqT, comb1, Mx, 2560, Cc, Ka, fc, fs);
  // GEMM2: cq @ [w_uq|w_qr] -> Qa (qc + rope(qr)), pre-scaled
  gemm256<2, ushort_t><<<dim3((Mx / 256) * (3072 / 256)), 512, 0, stream>>>(
      comb1, 1536, wuqT, Qa /*unused C*/, Mx, 3072, QRc, Qa, fc, fs);
  // GEMM3: ckv @ [w_uk|w_uv] -> Ka(kc) + vb
  gemm256<3, ushort_t><<<dim3((Mx / 256) * (4096 / 256)), 512, 0, stream>>>(
      comb1 + QRc, 1536, wukT, vb, Mx, 4096, KVRc, Ka, fc, fs);

  transpose_v<<<dim3(Tc / 32, HDc / 32, Bc * Hc), dim3(32, 8), 0, stream>>>(vb, 2048, vT);

  attn_kernel<<<dim3(Bc * Hc, 8), 512, 0, stream>>>(Qa, Ka, vT, O);

  // GEMM4: O @ w_o -> out [4096][2048] fp32
  gemm256<0, float><<<dim3((Mx / 256) * (Cc / 256)), 512, 0, stream>>>(
      O, Hc * HDc, woT, out, Mx, Cc, Hc * HDc, nullptr, nullptr, nullptr);
}